// Round 10
// baseline (302.572 us; speedup 1.0000x reference)
//
#include <hip/hip_runtime.h>

#define BN_EPS 1e-5f

using h8 = __attribute__((ext_vector_type(8))) _Float16;
using h4v = __attribute__((ext_vector_type(4))) _Float16;
using f4v = __attribute__((ext_vector_type(4))) float;

// workspace float offsets (proven layout). Slot/arena aliases:
//   sums1 (mlp1 slots, 256x256, plain stores)  = H3[0:65536)   (h3 written later)
//   sums3 (mlp3 slots, 256x256, plain stores)  = P2[0:65536)   (P2 dead then)
//   sums2 (mlp2 arena, 64x256, atomics)        = P4[0:16384)
//   sums4 (mlp4 arena, 64x256, atomics)        = H1[0:16384)   (zeroed in pq4)
// h4 is stored in MFMA C-layout per 64-row tile (8192 u16/tile):
//   idx(tile,row,col) = tile*8192 + ((cg*4+rt)*4+quad)*64 + cl*4 + i
//   where rt=(row>>4)&3, quad=(row>>2)&3, i=row&3, cg=col>>4, cl=col&15.
#define OFF_COEF 0        // coef2 only: a @ [0:128), shift @ [128:256)
#define OFF_CVEC 1024     // 128
#define OFF_H1 4096       // 4096x128 (aliased: aggraw; first 16384 = sums4)
#define OFF_P2 528384
#define OFF_Q2 1052672
#define OFF_H3 1576960
#define OFF_P4 2101248
#define OFF_Q4 2625536
#define OFF_W2P 3149824   // 16384 fp16 = 8192 floats each
#define OFF_W4P 3158016
#define OFF_WCP 3166208
#define OFF_H4B 3174400   // 258048x128 fp16: h2 then h4 in place
#define WS_BYTES 78757888ull

__device__ __forceinline__ float elu_f(float x) {
    return x > 0.f ? x : __expf(x) - 1.f;
}

// ---------------------------------------------------------------------------
// fp32 tile GEMM helpers. 16-row tiles double the block count on the
// grid-limited node-level kernels (mlp1p/pqf/mlp3 — proven r9 lever).
// ---------------------------------------------------------------------------

__device__ __forceinline__ void gemm16_globalW(const float* As, int lda,
                                               const float* __restrict__ Wg, int K,
                                               float acc[8], int tx, int ty) {
    const float4* Wg4 = (const float4*)Wg;
#pragma unroll 4
    for (int k = 0; k < K; ++k) {
        float a0 = As[ty * lda + k];
        float4 wa = Wg4[k * 32 + tx];
        float4 wb = Wg4[k * 32 + 16 + tx];
        acc[0] = fmaf(a0, wa.x, acc[0]);
        acc[1] = fmaf(a0, wa.y, acc[1]);
        acc[2] = fmaf(a0, wa.z, acc[2]);
        acc[3] = fmaf(a0, wa.w, acc[3]);
        acc[4] = fmaf(a0, wb.x, acc[4]);
        acc[5] = fmaf(a0, wb.y, acc[5]);
        acc[6] = fmaf(a0, wb.z, acc[6]);
        acc[7] = fmaf(a0, wb.w, acc[7]);
    }
}

__device__ __forceinline__ void bias_elu16(const float acc[8],
                                           const float* __restrict__ bias,
                                           float vals[8], int tx) {
    int ca = 4 * tx, cb = 64 + 4 * tx;
    float bv[8] = {bias[ca], bias[ca + 1], bias[ca + 2], bias[ca + 3],
                   bias[cb], bias[cb + 1], bias[cb + 2], bias[cb + 3]};
#pragma unroll
    for (int u = 0; u < 8; ++u)
        vals[u] = elu_f(acc[u] + bv[u]);
}

// 16-row stats -> per-block slot (plain stores; no zero-init needed).
__device__ __forceinline__ void stats_tail16_store(const float vals[8], float* red,
                                                   float* __restrict__ slot, int tid,
                                                   int tx, int ty) {
    __syncthreads();
    int ca = 4 * tx, cb = 64 + 4 * tx;
#pragma unroll
    for (int u = 0; u < 4; ++u) {
        red[ty * 128 + ca + u] = vals[u];
        red[2048 + ty * 128 + ca + u] = vals[u] * vals[u];
        red[ty * 128 + cb + u] = vals[u + 4];
        red[2048 + ty * 128 + cb + u] = vals[u + 4] * vals[u + 4];
    }
    __syncthreads();
    if (tid < 128) {
        float s = 0.f, q = 0.f;
#pragma unroll
        for (int t = 0; t < 16; ++t) {
            s += red[t * 128 + tid];
            q += red[2048 + t * 128 + tid];
        }
        slot[tid] = s;
        slot[128 + tid] = q;
    }
}

// ---------------------------------------------------------------------------
// MFMA helpers (proven).
// ---------------------------------------------------------------------------

// single-tile MFMA GEMM: A from row-major XOR-swizzled LDS tile [64][128] fp16
// (LDS row r holds global 16B-chunk c at position c^(r&7); verified r2/r5/r7).
__device__ __forceinline__ void gemm1_swz(const _Float16* X,
                                          const _Float16* __restrict__ wp,
                                          f4v acc[4][2], int lane, int w,
                                          int cl, int quad) {
#pragma unroll
    for (int kc = 0; kc < 4; ++kc) {
        h8 bf0 = *(const h8*)&wp[(((w * 2 + 0) * 4 + kc) * 64 + lane) * 8];
        h8 bf1 = *(const h8*)&wp[(((w * 2 + 1) * 4 + kc) * 64 + lane) * 8];
        int co = ((kc * 4 + quad) ^ (cl & 7)) << 3;
        h8 af[4];
#pragma unroll
        for (int rt = 0; rt < 4; ++rt)
            af[rt] = *(const h8*)&X[(rt * 16 + cl) * 128 + co];
#pragma unroll
        for (int rt = 0; rt < 4; ++rt) {
            acc[rt][0] = __builtin_amdgcn_mfma_f32_16x16x32_f16(af[rt], bf0, acc[rt][0], 0, 0, 0);
            acc[rt][1] = __builtin_amdgcn_mfma_f32_16x16x32_f16(af[rt], bf1, acc[rt][1], 0, 0, 0);
        }
    }
}

// ---------------------------------------------------------------------------
// Kernels
// ---------------------------------------------------------------------------

// mlp1, round-10: 16-row tiles (256 compute blocks; was 128 = half the CUs
// idle) + fused prep (blocks 256..336: zero sums2+cvec, pack w2/w4 layer-2
// weights to fp16 frag layout). Slot stats -> 256 slots in the h3 arena.
__global__ __launch_bounds__(256) void k_mlp1p(const float* __restrict__ x,
                                               const float* __restrict__ w1,
                                               const float* __restrict__ b1,
                                               const float* __restrict__ w2,
                                               const float* __restrict__ b2,
                                               float* __restrict__ h1,
                                               float* __restrict__ slots,
                                               float* __restrict__ sums2,
                                               float* __restrict__ cvec,
                                               const float* __restrict__ w2src,
                                               _Float16* __restrict__ w2p,
                                               const float* __restrict__ w4src,
                                               _Float16* __restrict__ w4p) {
    __shared__ float Xs[16 * 44];
    __shared__ float As[4224];  // gemm tile uses 16*132=2112; stats tail uses 4096
    int tid = threadIdx.x;
    int blk = blockIdx.x;
    if (blk >= 256) {
        if (blk < 321) {  // zeroing (65 blocks)
            int i = (blk - 256) * 256 + tid;
            if (i < 16384) sums2[i] = 0.f;
            else if (i < 16512) cvec[i - 16384] = 0.f;
        } else {  // weight packing (8 + 8 blocks)
            int second = blk >= 329;
            const float* src = second ? w4src : w2src;
            _Float16* wp = second ? w4p : w2p;
            int flat = (blk - (second ? 329 : 321)) * 256 + tid;  // 0..2047
            int g = flat >> 6, L = flat & 63;
            int ct = g >> 2, kc = g & 3;
            int nn = ct * 16 + (L & 15), k0 = kc * 32 + (L >> 4) * 8;
            h8 v;
#pragma unroll
            for (int j = 0; j < 8; ++j) v[j] = (_Float16)src[(k0 + j) * 128 + nn];
            *(h8*)&wp[flat * 8] = v;
        }
        return;
    }
    int tx = tid & 15, ty = tid >> 4;
    int r0 = blk * 16;
    for (int idx = tid; idx < 16 * 40; idx += 256) {
        int r = idx / 40, k = idx - r * 40;
        int rr = r0 + r, b = rr >> 6, n = rr & 63, t = k >> 2, d = k & 3;
        Xs[r * 44 + k] = x[((b * 10 + t) * 64 + n) * 4 + d];
    }
    __syncthreads();
    float acc[8] = {};
    gemm16_globalW(Xs, 44, w1, 40, acc, tx, ty);
    float vals[8];
    bias_elu16(acc, b1, vals, tx);
    int ca = 4 * tx, cb = 64 + 4 * tx;
#pragma unroll
    for (int u = 0; u < 4; ++u) {
        As[ty * 132 + ca + u] = vals[u];
        As[ty * 132 + cb + u] = vals[u + 4];
    }
    __syncthreads();
    float acc2[8] = {};
    gemm16_globalW(As, 132, w2, 128, acc2, tx, ty);
    float vals2[8];
    bias_elu16(acc2, b2, vals2, tx);
    int r = r0 + ty;
    *(float4*)(h1 + r * 128 + 4 * tx) = make_float4(vals2[0], vals2[1], vals2[2], vals2[3]);
    *(float4*)(h1 + r * 128 + 64 + 4 * tx) = make_float4(vals2[4], vals2[5], vals2[6], vals2[7]);
    stats_tail16_store(vals2, As, slots + blk * 256, tid, tx, ty);
}

// P/Q precompute with fused BN-coef derivation from nslots plain-store slots.
// 16-row tiles, grid 512 (2 blocks/CU). Optionally zeroes zero4[0:16384)
// distributed across the 512 blocks (pq4).
__global__ __launch_bounds__(256) void k_pqf(const float* __restrict__ h,
                                             const float* __restrict__ slots,
                                             int nslots,
                                             const float* __restrict__ g,
                                             const float* __restrict__ beta,
                                             const float* __restrict__ w,
                                             float* __restrict__ P, float* __restrict__ Q,
                                             float* __restrict__ zero4) {
    __shared__ float Cf[256];
    __shared__ float As[16 * 132];
    int tid = threadIdx.x, tx = tid & 15, ty = tid >> 4;
    int half = blockIdx.x >> 8;
    int r0 = (blockIdx.x & 255) * 16;
    if (zero4 && tid < 32) zero4[blockIdx.x * 32 + tid] = 0.f;
    if (tid < 128) {
        int c = tid;
        float s = 0.f, q = 0.f;
#pragma unroll 8
        for (int t = 0; t < nslots; ++t) {
            s += slots[t * 256 + c];
            q += slots[t * 256 + 128 + c];
        }
        float mean = s * (1.f / 4096.f);
        float var = q * (1.f / 4096.f) - mean * mean;
        float a = g[c] * rsqrtf(var + BN_EPS);
        Cf[c] = a;
        Cf[128 + c] = beta[c] - mean * a;
    }
    __syncthreads();
    const float* Wg = w + half * 128 * 128;
    float* out = half ? Q : P;
    const float4* h4p = (const float4*)h;
#pragma unroll
    for (int i = 0; i < 2; ++i) {
        int f4 = tid + i * 256;
        int r = f4 >> 5, c4 = f4 & 31;
        float4 hv = h4p[(r0 + r) * 32 + c4];
        int cb = c4 * 4;
        float4 v;
        v.x = Cf[cb] * hv.x + Cf[128 + cb];
        v.y = Cf[cb + 1] * hv.y + Cf[128 + cb + 1];
        v.z = Cf[cb + 2] * hv.z + Cf[128 + cb + 2];
        v.w = Cf[cb + 3] * hv.w + Cf[128 + cb + 3];
        *(float4*)(As + r * 132 + c4 * 4) = v;
    }
    __syncthreads();
    float acc[8] = {};
    gemm16_globalW(As, 132, Wg, 128, acc, tx, ty);
    int r = r0 + ty;
    *(float4*)(out + r * 128 + 4 * tx) = make_float4(acc[0], acc[1], acc[2], acc[3]);
    *(float4*)(out + r * 128 + 64 + 4 * tx) = make_float4(acc[4], acc[5], acc[6], acc[7]);
}

// Recv-major fused mlp2 + edge2node + h2 materialization (round-5 proven:
// coalesced stage into swizzled row-major LDS, gemm1_swz, reordered h2 write).
__global__ __launch_bounds__(256, 6) void k_mlp2agg(const float* __restrict__ P2,
                                                    const float* __restrict__ Q2,
                                                    const float* __restrict__ b1,
                                                    const _Float16* __restrict__ w2p,
                                                    const float* __restrict__ b2,
                                                    float* __restrict__ aggraw,
                                                    _Float16* __restrict__ h2,
                                                    float* __restrict__ st) {
    __shared__ __align__(16) _Float16 Afr[9216];
    int tid = threadIdx.x;
    int lane = tid & 63, w = tid >> 6, cl = lane & 15, quad = lane >> 4;
    int b = blockIdx.x >> 6, n0 = blockIdx.x & 63;
    float* stc = st + n0 * 256;
    // --- coalesced stage into row-major swizzled tile X[64][128] fp16 ---
    {
        int c4 = tid & 31;    // float4 column 0..31
        int rsub = tid >> 5;  // 0..7
        const float4* Qr = (const float4*)(Q2 + (b * 64 + n0) * 128);
        const float4* B1 = (const float4*)b1;
        float4 qv = Qr[c4];
        float4 bv = B1[c4];
        float qbx = qv.x + bv.x, qby = qv.y + bv.y;
        float qbz = qv.z + bv.z, qbw = qv.w + bv.w;
        const float4* P4p = (const float4*)(P2 + (size_t)b * 64 * 128);
#pragma unroll
        for (int it = 0; it < 8; ++it) {
            int r = it * 8 + rsub;
            int s0 = (r < 63) ? (r + (r >= n0 ? 1 : 0)) : n0;  // row 63: dummy
            float4 p = P4p[s0 * 32 + c4];
            h4v v;
            v[0] = (_Float16)elu_f(p.x + qbx);
            v[1] = (_Float16)elu_f(p.y + qby);
            v[2] = (_Float16)elu_f(p.z + qbz);
            v[3] = (_Float16)elu_f(p.w + qbw);
            int off = r * 128 + ((((c4 >> 1) ^ (r & 7)) << 3) | ((c4 & 1) << 2));
            *(h4v*)&Afr[off] = v;
        }
    }
    __syncthreads();
    f4v acc[4][2];
#pragma unroll
    for (int rt = 0; rt < 4; ++rt)
#pragma unroll
        for (int c = 0; c < 2; ++c)
            acc[rt][c] = (f4v){0.f, 0.f, 0.f, 0.f};
    gemm1_swz(Afr, w2p, acc, lane, w, cl, quad);
    float v0[2][4][4];
#pragma unroll
    for (int ctl = 0; ctl < 2; ++ctl) {
        int col = (w * 2 + ctl) * 16 + cl;
        float bias = b2[col];
        float a0 = 0.f, sq = 0.f;
#pragma unroll
        for (int rt = 0; rt < 4; ++rt)
#pragma unroll
            for (int i = 0; i < 4; ++i) {
                int row = rt * 16 + quad * 4 + i;
                float va = elu_f(acc[rt][ctl][i] + bias);
                if (row == 63) va = 0.f;
                v0[ctl][rt][i] = va;
                a0 += va;
                sq += va * va;
            }
        a0 += __shfl_xor(a0, 16);
        sq += __shfl_xor(sq, 16);
        a0 += __shfl_xor(a0, 32);
        sq += __shfl_xor(sq, 32);
        if (quad == 0) {
            aggraw[(b * 64 + n0) * 128 + col] = a0;
            atomicAdd(stc + col, a0);
            atomicAdd(stc + 128 + col, sq);
        }
    }
    __syncthreads();
    unsigned short* T0 = (unsigned short*)Afr;
#pragma unroll
    for (int ctl = 0; ctl < 2; ++ctl) {
        int col = (w * 2 + ctl) * 16 + cl;
#pragma unroll
        for (int rt = 0; rt < 4; ++rt)
#pragma unroll
            for (int i = 0; i < 4; ++i) {
                int row = rt * 16 + quad * 4 + i;
                _Float16 ha = (_Float16)v0[ctl][rt][i];
                T0[row * 144 + col] = *(unsigned short*)&ha;
            }
    }
    __syncthreads();
    {
        int rr = tid >> 2, cq = tid & 3;
        if (rr < 63) {
            int s0 = rr + (rr >= n0 ? 1 : 0);
            int e0 = s0 * 63 + (s0 > n0 ? n0 : n0 - 1);
            unsigned short* d0 = (unsigned short*)h2 + ((size_t)b * 4032 + e0) * 128;
#pragma unroll
            for (int i = 0; i < 4; ++i) {
                int off = i * 32 + cq * 8;  // row's 4 lanes contiguous (64B)
                *(uint4*)(d0 + off) = *(uint4*)&T0[rr * 144 + off];
            }
        }
    }
}

// fused BN2-finalize + wcprep: block k derives coef2[k] pair from the 64-slot
// atomic arena, writes it (for mlp3), then scales W4_1[256+k][:] into wcp and
// accumulates cvec.
__global__ __launch_bounds__(128) void k_wcfin(const float* __restrict__ sums2,
                                               const float* __restrict__ g2,
                                               const float* __restrict__ be2,
                                               const float* __restrict__ w41,
                                               _Float16* __restrict__ wcp,
                                               float* __restrict__ cvec,
                                               float* __restrict__ coef2) {
    __shared__ float red[128];
    __shared__ float pr[2];
    int k = blockIdx.x, c = threadIdx.x;  // 128 threads
    red[c] = (c < 64) ? sums2[c * 256 + k] : sums2[(c - 64) * 256 + 128 + k];
    __syncthreads();
    if (c == 0) {
        float s = 0.f, q = 0.f;
#pragma unroll 8
        for (int t = 0; t < 64; ++t) {
            s += red[t];
            q += red[64 + t];
        }
        float mean = s * (1.f / 258048.f);
        float var = q * (1.f / 258048.f) - mean * mean;
        float a = g2[k] * rsqrtf(var + BN_EPS);
        pr[0] = a;
        pr[1] = be2[k] - mean * a;
        coef2[k] = a;
        coef2[128 + k] = pr[1];
    }
    __syncthreads();
    float a2k = pr[0], sh2k = pr[1];
    float wv = w41[(256 + k) * 128 + c];
    int g = (c >> 4) * 4 + (k >> 5);
    int L = ((k >> 3) & 3) * 16 + (c & 15);
    int j = k & 7;
    wcp[(g * 64 + L) * 8 + j] = (_Float16)(a2k * wv);
    atomicAdd(&cvec[c], sh2k * wv);
}

// mlp3 (round-9 proven): 16-row tiles, 256 blocks, 256 stat slots.
__global__ __launch_bounds__(256) void k_mlp3(const float* __restrict__ raw,
                                              const float* __restrict__ coef2,
                                              const float* __restrict__ w1,
                                              const float* __restrict__ b1,
                                              const float* __restrict__ w2,
                                              const float* __restrict__ b2,
                                              float* __restrict__ h3,
                                              float* __restrict__ slots) {
    __shared__ float As[4224];  // staging/GEMM uses 16*132=2112; stats tail uses 4096
    int tid = threadIdx.x, tx = tid & 15, ty = tid >> 4;
    int r0 = blockIdx.x * 16;
    const float4* in4 = (const float4*)raw;
    const float4* av = (const float4*)coef2;
    const float4* cv = (const float4*)(coef2 + 128);
    const float inv63 = 1.f / 63.f;
#pragma unroll
    for (int i = 0; i < 2; ++i) {
        int f4 = tid + i * 256;
        int r = f4 >> 5, c4 = f4 & 31;
        float4 hv = in4[(r0 + r) * 32 + c4];
        float4 a = av[c4], c = cv[c4];
        float4 v;
        v.x = a.x * hv.x * inv63 + c.x;
        v.y = a.y * hv.y * inv63 + c.y;
        v.z = a.z * hv.z * inv63 + c.z;
        v.w = a.w * hv.w * inv63 + c.w;
        *(float4*)(As + r * 132 + c4 * 4) = v;
    }
    __syncthreads();
    float acc[8] = {};
    gemm16_globalW(As, 132, w1, 128, acc, tx, ty);
    float vals[8];
    bias_elu16(acc, b1, vals, tx);
    __syncthreads();
    int ca = 4 * tx, cb = 64 + 4 * tx;
#pragma unroll
    for (int u = 0; u < 4; ++u) {
        As[ty * 132 + ca + u] = vals[u];
        As[ty * 132 + cb + u] = vals[u + 4];
    }
    __syncthreads();
    float acc2[8] = {};
    gemm16_globalW(As, 132, w2, 128, acc2, tx, ty);
    float vals2[8];
    bias_elu16(acc2, b2, vals2, tx);
    int r = r0 + ty;
    *(float4*)(h3 + r * 128 + 4 * tx) = make_float4(vals2[0], vals2[1], vals2[2], vals2[3]);
    *(float4*)(h3 + r * 128 + 64 + 4 * tx) = make_float4(vals2[4], vals2[5], vals2[6], vals2[7]);
    stats_tail16_store(vals2, As, slots + blockIdx.x * 256, tid, tx, ty);
}

// mlp4 edge kernel, round-10: P/Q/bias gather moved BEFORE the staging
// barrier into v0 (the gather's 32 scattered loads fly concurrently with the
// 4 staging loads and are drained by the same pre-barrier waitcnt — their
// latency no longer serializes between gemm1 and tile2). epi1 = elu(acc+v0).
// +32 live VGPRs across gemm1 -> bounds (256,5) (102-VGPR budget; achieved
// occupancy was 46% < the new 62% cap, so no loss; (256,6)@~75 VGPR risked a
// round-6-style spill).
__global__ __launch_bounds__(256, 5) void k_mlp4r3(const _Float16* __restrict__ h2,
                                                   const float* __restrict__ P4,
                                                   const float* __restrict__ Q4,
                                                   const _Float16* __restrict__ wcp,
                                                   const float* __restrict__ cvec,
                                                   const float* __restrict__ b1,
                                                   const _Float16* __restrict__ w4p2,
                                                   const float* __restrict__ b2,
                                                   unsigned short* __restrict__ h4,
                                                   float* __restrict__ st) {
    __shared__ __align__(16) _Float16 Afr[8192];
    int tid = threadIdx.x;
    int lane = tid & 63, w = tid >> 6, cl = lane & 15, quad = lane >> 4;
    unsigned t0 = blockIdx.x;
    unsigned b0 = t0 / 63;
    unsigned e00 = (t0 - b0 * 63) * 64;
    float* stc = st + (blockIdx.x & 63) * 256;
    {
        const _Float16* hb = h2 + (size_t)t0 * 8192;
#pragma unroll
        for (int i = 0; i < 4; ++i) {
            int u = tid + i * 256;
            int r = u >> 4, c = u & 15;
            h8 v = *(const h8*)&hb[r * 128 + c * 8];
            *(h8*)&Afr[r * 128 + ((c ^ (r & 7)) << 3)] = v;
        }
    }
    // pre-gather: qsum = P[send] + Q[recv] + b1 + cvec, held across gemm1
    float v0[4][2][4];
    {
        int col0 = w * 32 + cl, col1 = col0 + 16;
        float base0 = b1[col0] + cvec[col0];
        float base1 = b1[col1] + cvec[col1];
        unsigned sA0 = e00 / 63;
        unsigned baseE0 = sA0 * 63;
        unsigned eB0 = baseE0 + 63;
        unsigned sB0 = sA0 < 63u ? sA0 + 1u : sA0;
        const float* PA0 = P4 + (b0 * 64 + sA0) * 128;
        const float* PB0 = P4 + (b0 * 64 + sB0) * 128;
        float pA0c0 = PA0[col0], pA0c1 = PA0[col1];
        float pB0c0 = PB0[col0], pB0c1 = PB0[col1];
        const float* Qb0 = Q4 + (size_t)b0 * 8192;
#pragma unroll
        for (int rt = 0; rt < 4; ++rt)
#pragma unroll
            for (int i = 0; i < 4; ++i) {
                int rr = rt * 16 + quad * 4 + i;
                unsigned e = e00 + rr;
                bool hi = e >= eB0;
                unsigned s = hi ? sB0 : sA0;
                unsigned jj = e - (hi ? eB0 : baseE0);
                unsigned rv = jj + (jj >= s ? 1u : 0u);
                const float* Qr = Qb0 + rv * 128;
                float p0 = hi ? pB0c0 : pA0c0, p1 = hi ? pB0c1 : pA0c1;
                v0[rt][0][i] = p0 + Qr[col0] + base0;
                v0[rt][1][i] = p1 + Qr[col1] + base1;
            }
    }
    __syncthreads();
    f4v acc[4][2];
#pragma unroll
    for (int rt = 0; rt < 4; ++rt)
#pragma unroll
        for (int c = 0; c < 2; ++c)
            acc[rt][c] = (f4v){0.f, 0.f, 0.f, 0.f};
    gemm1_swz(Afr, wcp, acc, lane, w, cl, quad);
    // epi1: activation on acc + pre-gathered offset
#pragma unroll
    for (int rt = 0; rt < 4; ++rt)
#pragma unroll
        for (int i = 0; i < 4; ++i) {
            v0[rt][0][i] = elu_f(acc[rt][0][i] + v0[rt][0][i]);
            v0[rt][1][i] = elu_f(acc[rt][1][i] + v0[rt][1][i]);
        }
    __syncthreads();
    // tile2: write intermediate X2[row][col] into the same swizzled layout
    {
        int colb0 = w * 32 + cl, colb1 = colb0 + 16;
        int cc0 = colb0 >> 3, cj0 = colb0 & 7;
        int cc1 = colb1 >> 3, cj1 = colb1 & 7;
#pragma unroll
        for (int rt = 0; rt < 4; ++rt)
#pragma unroll
            for (int i = 0; i < 4; ++i) {
                int row = rt * 16 + quad * 4 + i;
                int rx = row & 7;
                Afr[row * 128 + (((cc0 ^ rx) << 3) | cj0)] = (_Float16)v0[rt][0][i];
                Afr[row * 128 + (((cc1 ^ rx) << 3) | cj1)] = (_Float16)v0[rt][1][i];
            }
    }
    __syncthreads();
#pragma unroll
    for (int rt = 0; rt < 4; ++rt)
#pragma unroll
        for (int c = 0; c < 2; ++c)
            acc[rt][c] = (f4v){0.f, 0.f, 0.f, 0.f};
    gemm1_swz(Afr, w4p2, acc, lane, w, cl, quad);
#pragma unroll
    for (int ctl = 0; ctl < 2; ++ctl) {
        int col = (w * 2 + ctl) * 16 + cl;
        float bias = b2[col];
        float s1 = 0.f, s2 = 0.f;
#pragma unroll
        for (int rt = 0; rt < 4; ++rt)
#pragma unroll
            for (int i = 0; i < 4; ++i) {
                float va = elu_f(acc[rt][ctl][i] + bias);
                v0[rt][ctl][i] = va;
                s1 += va;
                s2 += va * va;
            }
        s1 += __shfl_xor(s1, 16);
        s2 += __shfl_xor(s2, 16);
        s1 += __shfl_xor(s1, 32);
        s2 += __shfl_xor(s2, 32);
        if (quad == 0) {
            atomicAdd(stc + col, s1);
            atomicAdd(stc + 128 + col, s2);
        }
    }
    // direct C-layout store: idx = ((cg*4+rt)*4+quad)*64 + cl*4 + i
    {
        unsigned short* o0 = h4 + (size_t)t0 * 8192;
#pragma unroll
        for (int ctl = 0; ctl < 2; ++ctl) {
            int cg = w * 2 + ctl;
#pragma unroll
            for (int rt = 0; rt < 4; ++rt) {
                int idx = ((cg * 4 + rt) * 4 + quad) * 64 + cl * 4;
                h4v a;
#pragma unroll
                for (int i = 0; i < 4; ++i) a[i] = (_Float16)v0[rt][ctl][i];
                *(h4v*)(o0 + idx) = a;
            }
        }
    }
}

// fused BN4-finalize + fc output, reading h4 in C-layout. BN is folded into
// the fc weights: u_k[c] = a[c]*w[c][k]; out = h.u_k + C_k with
// C_k = sum_c sh[c]*w[c][k] + fcb[k].
__global__ __launch_bounds__(256) void k_outf(const unsigned short* __restrict__ h4,
                                              const float* __restrict__ sums4,
                                              const float* __restrict__ g4,
                                              const float* __restrict__ be4,
                                              const float* __restrict__ fcw,
                                              const float* __restrict__ fcb,
                                              float* __restrict__ out) {
    __shared__ float U0[128];
    __shared__ float U1[128];
    __shared__ float Cp[4];
    int tid = threadIdx.x;
    if (tid < 128) {
        int c = tid;
        float s = 0.f, q = 0.f;
#pragma unroll 8
        for (int t = 0; t < 64; ++t) {
            s += sums4[t * 256 + c];
            q += sums4[t * 256 + 128 + c];
        }
        float mean = s * (1.f / 258048.f);
        float var = q * (1.f / 258048.f) - mean * mean;
        float a = g4[c] * rsqrtf(var + BN_EPS);
        float sh = be4[c] - mean * a;
        float w0 = fcw[2 * c], w1 = fcw[2 * c + 1];
        U0[c] = a * w0;
        U1[c] = a * w1;
        float p0 = sh * w0, p1 = sh * w1;
#pragma unroll
        for (int off = 1; off < 64; off <<= 1) {
            p0 += __shfl_xor(p0, off);
            p1 += __shfl_xor(p1, off);
        }
        if ((tid & 63) == 0) {
            Cp[(tid >> 6) * 2] = p0;
            Cp[(tid >> 6) * 2 + 1] = p1;
        }
    }
    __syncthreads();
    float C0 = Cp[0] + Cp[2] + fcb[0];
    float C1 = Cp[1] + Cp[3] + fcb[1];
    int lane = tid & 63, w = tid >> 6;
    int quad = lane >> 4, cl = lane & 15;
    float u0r[8], u1r[8];
#pragma unroll
    for (int cg = 0; cg < 8; ++cg) {
        u0r[cg] = U0[cg * 16 + cl];
        u1r[cg] = U1[cg * 16 + cl];
    }
    size_t tile = (size_t)blockIdx.x * 4 + w;
    const unsigned short* hb = h4 + tile * 8192;
#pragma unroll
    for (int rt = 0; rt < 4; ++rt) {
        float s00 = 0.f, s01 = 0.f, s02 = 0.f, s03 = 0.f;
        float s10 = 0.f, s11 = 0.f, s12 = 0.f, s13 = 0.f;
#pragma unroll
        for (int cg = 0; cg < 8; ++cg) {
            h4v hv = *(const h4v*)(hb + ((cg * 4 + rt) * 4 + quad) * 64 + cl * 4);
            float u0 = u0r[cg], u1 = u1r[cg];
            float x0 = (float)hv[0], x1 = (float)hv[1];
            float x2 = (float)hv[2], x3 = (float)hv[3];
            s00 = fmaf(x0, u0, s00); s01 = fmaf(x1, u0, s01);
            s02 = fmaf(x2, u0, s02); s03 = fmaf(x3, u0, s03);
            s10 = fmaf(x0, u1, s10); s11 = fmaf(x1, u1, s11);
            s12 = fmaf(x2, u1, s12); s13 = fmaf(x3, u1, s13);
        }
#pragma unroll
        for (int off = 1; off < 16; off <<= 1) {
            s00 += __shfl_xor(s00, off); s01 += __shfl_xor(s01, off);
            s02 += __shfl_xor(s02, off); s03 += __shfl_xor(s03, off);
            s10 += __shfl_xor(s10, off); s11 += __shfl_xor(s11, off);
            s12 += __shfl_xor(s12, off); s13 += __shfl_xor(s13, off);
        }
        if (cl == 0) {
            size_t R = tile * 64 + rt * 16 + quad * 4;
            *(float4*)(out + R * 2) =
                make_float4(s00 + C0, s10 + C1, s01 + C0, s11 + C1);
            *(float4*)(out + R * 2 + 4) =
                make_float4(s02 + C0, s12 + C1, s03 + C0, s13 + C1);
        }
    }
}

// ---------------------------------------------------------------------------

extern "C" void kernel_launch(void* const* d_in, const int* in_sizes, int n_in,
                              void* d_out, int out_size, void* d_ws, size_t ws_size,
                              hipStream_t stream) {
    const float* x = (const float*)d_in[0];
    const float* m1_w1 = (const float*)d_in[1];
    const float* m1_b1 = (const float*)d_in[2];
    const float* m1_w2 = (const float*)d_in[3];
    const float* m1_b2 = (const float*)d_in[4];
    const float* m1_g = (const float*)d_in[5];
    const float* m1_be = (const float*)d_in[6];
    const float* m2_w1 = (const float*)d_in[7];
    const float* m2_b1 = (const float*)d_in[8];
    const float* m2_w2 = (const float*)d_in[9];
    const float* m2_b2 = (const float*)d_in[10];
    const float* m2_g = (const float*)d_in[11];
    const float* m2_be = (const float*)d_in[12];
    const float* m3_w1 = (const float*)d_in[13];
    const float* m3_b1 = (const float*)d_in[14];
    const float* m3_w2 = (const float*)d_in[15];
    const float* m3_b2 = (const float*)d_in[16];
    const float* m3_g = (const float*)d_in[17];
    const float* m3_be = (const float*)d_in[18];
    const float* m4_w1 = (const float*)d_in[19];
    const float* m4_b1 = (const float*)d_in[20];
    const float* m4_w2 = (const float*)d_in[21];
    const float* m4_b2 = (const float*)d_in[22];
    const float* m4_g = (const float*)d_in[23];
    const float* m4_be = (const float*)d_in[24];
    const float* fc_w = (const float*)d_in[25];
    const float* fc_b = (const float*)d_in[26];
    float* out = (float*)d_out;

    float* W = (float*)d_ws;
    float* coef2 = W + OFF_COEF;
    float* cvec = W + OFF_CVEC;
    float* h1 = W + OFF_H1;            // aliased: aggraw; sums4 = h1[0:16384)
    float* aggraw = h1;
    float* sums4 = h1;
    float* P2 = W + OFF_P2;            // sums3 slots = P2[0:65536) (P2 dead then)
    float* sums3 = P2;
    float* Q2 = W + OFF_Q2;
    float* h3 = W + OFF_H3;            // sums1 slots = h3[0:65536) (h3 written later)
    float* sums1 = h3;
    float* P4 = W + OFF_P4;            // sums2 arena = P4[0:16384)
    float* sums2 = P4;
    float* Q4 = W + OFF_Q4;
    _Float16* w2p2 = (_Float16*)(W + OFF_W2P);
    _Float16* w4p2 = (_Float16*)(W + OFF_W4P);
    _Float16* wcp = (_Float16*)(W + OFF_WCP);
    _Float16* h2f = (_Float16*)(W + OFF_H4B);             // h2 (fp16), then
    unsigned short* h4b = (unsigned short*)(W + OFF_H4B); // h4 (fp16, C-layout) in place

    if (ws_size < WS_BYTES) return;  // safe-fail diagnostic (no OOB fault)

    k_mlp1p<<<337, 256, 0, stream>>>(x, m1_w1, m1_b1, m1_w2, m1_b2, h1, sums1,
                                     sums2, cvec, m2_w2, w2p2, m4_w2, w4p2);
    k_pqf<<<512, 256, 0, stream>>>(h1, sums1, 256, m1_g, m1_be, m2_w1, P2, Q2, nullptr);
    k_mlp2agg<<<4096, 256, 0, stream>>>(P2, Q2, m2_b1, w2p2, m2_b2, aggraw, h2f, sums2);
    k_wcfin<<<128, 128, 0, stream>>>(sums2, m2_g, m2_be, m4_w1, wcp, cvec, coef2);
    k_mlp3<<<256, 256, 0, stream>>>(aggraw, coef2, m3_w1, m3_b1, m3_w2, m3_b2, h3, sums3);
    k_pqf<<<512, 256, 0, stream>>>(h3, sums3, 256, m3_g, m3_be, m4_w1, P4, Q4, sums4);
    k_mlp4r3<<<4032, 256, 0, stream>>>(h2f, P4, Q4, wcp, cvec, m4_b1, w4p2, m4_b2,
                                       h4b, sums4);
    k_outf<<<1008, 256, 0, stream>>>(h4b, sums4, m4_g, m4_be, fc_w, fc_b, out);
}

// Round 11
// 291.824 us; speedup vs baseline: 1.0368x; 1.0368x over previous
//
#include <hip/hip_runtime.h>

#define BN_EPS 1e-5f

using h8 = __attribute__((ext_vector_type(8))) _Float16;
using h4v = __attribute__((ext_vector_type(4))) _Float16;
using f4v = __attribute__((ext_vector_type(4))) float;

// workspace float offsets (proven layout). Slot/arena aliases:
//   sums1 (mlp1 slots, 256x256, plain stores)  = H3[0:65536)   (h3 written later)
//   sums3 (mlp3 slots, 256x256, plain stores)  = P2[0:65536)   (P2 dead then)
//   sums2 (mlp2 arena, 64x256, atomics)        = P4[0:16384)
//   sums4 (mlp4 arena, 64x256, atomics)        = H1[0:16384)   (zeroed in pq4)
// h4 is stored in MFMA C-layout per 64-row tile (8192 u16/tile):
//   idx(tile,row,col) = tile*8192 + ((cg*4+rt)*4+quad)*64 + cl*4 + i
//   where rt=(row>>4)&3, quad=(row>>2)&3, i=row&3, cg=col>>4, cl=col&15.
// REGALLOC RULE (proven r6 & r10): k_mlp4r3 cannot hold ANY extra live state
// across its GEMMs — both attempts spilled (+90 MB scratch traffic). The
// gather-after-gemm1 ordering and (256,6) bounds are load-bearing.
#define OFF_COEF 0        // coef2 only: a @ [0:128), shift @ [128:256)
#define OFF_CVEC 1024     // 128
#define OFF_H1 4096       // 4096x128 (aliased: aggraw; first 16384 = sums4)
#define OFF_P2 528384
#define OFF_Q2 1052672
#define OFF_H3 1576960
#define OFF_P4 2101248
#define OFF_Q4 2625536
#define OFF_W2P 3149824   // 16384 fp16 = 8192 floats each
#define OFF_W4P 3158016
#define OFF_WCP 3166208
#define OFF_H4B 3174400   // 258048x128 fp16: h2 then h4 in place
#define WS_BYTES 78757888ull

__device__ __forceinline__ float elu_f(float x) {
    return x > 0.f ? x : __expf(x) - 1.f;
}

// ---------------------------------------------------------------------------
// fp32 tile GEMM helpers. 16-row tiles double the block count on the
// grid-limited node-level kernels (mlp1p/pqf/mlp3 — proven r9/r10 lever).
// ---------------------------------------------------------------------------

__device__ __forceinline__ void gemm16_globalW(const float* As, int lda,
                                               const float* __restrict__ Wg, int K,
                                               float acc[8], int tx, int ty) {
    const float4* Wg4 = (const float4*)Wg;
#pragma unroll 4
    for (int k = 0; k < K; ++k) {
        float a0 = As[ty * lda + k];
        float4 wa = Wg4[k * 32 + tx];
        float4 wb = Wg4[k * 32 + 16 + tx];
        acc[0] = fmaf(a0, wa.x, acc[0]);
        acc[1] = fmaf(a0, wa.y, acc[1]);
        acc[2] = fmaf(a0, wa.z, acc[2]);
        acc[3] = fmaf(a0, wa.w, acc[3]);
        acc[4] = fmaf(a0, wb.x, acc[4]);
        acc[5] = fmaf(a0, wb.y, acc[5]);
        acc[6] = fmaf(a0, wb.z, acc[6]);
        acc[7] = fmaf(a0, wb.w, acc[7]);
    }
}

__device__ __forceinline__ void bias_elu16(const float acc[8],
                                           const float* __restrict__ bias,
                                           float vals[8], int tx) {
    int ca = 4 * tx, cb = 64 + 4 * tx;
    float bv[8] = {bias[ca], bias[ca + 1], bias[ca + 2], bias[ca + 3],
                   bias[cb], bias[cb + 1], bias[cb + 2], bias[cb + 3]};
#pragma unroll
    for (int u = 0; u < 8; ++u)
        vals[u] = elu_f(acc[u] + bv[u]);
}

// 16-row stats -> per-block slot (plain stores; no zero-init needed).
__device__ __forceinline__ void stats_tail16_store(const float vals[8], float* red,
                                                   float* __restrict__ slot, int tid,
                                                   int tx, int ty) {
    __syncthreads();
    int ca = 4 * tx, cb = 64 + 4 * tx;
#pragma unroll
    for (int u = 0; u < 4; ++u) {
        red[ty * 128 + ca + u] = vals[u];
        red[2048 + ty * 128 + ca + u] = vals[u] * vals[u];
        red[ty * 128 + cb + u] = vals[u + 4];
        red[2048 + ty * 128 + cb + u] = vals[u + 4] * vals[u + 4];
    }
    __syncthreads();
    if (tid < 128) {
        float s = 0.f, q = 0.f;
#pragma unroll
        for (int t = 0; t < 16; ++t) {
            s += red[t * 128 + tid];
            q += red[2048 + t * 128 + tid];
        }
        slot[tid] = s;
        slot[128 + tid] = q;
    }
}

// ---------------------------------------------------------------------------
// MFMA helpers (proven).
// ---------------------------------------------------------------------------

// single-tile MFMA GEMM: A from row-major XOR-swizzled LDS tile [64][128] fp16
// (LDS row r holds global 16B-chunk c at position c^(r&7); verified r2/r5/r7).
__device__ __forceinline__ void gemm1_swz(const _Float16* X,
                                          const _Float16* __restrict__ wp,
                                          f4v acc[4][2], int lane, int w,
                                          int cl, int quad) {
#pragma unroll
    for (int kc = 0; kc < 4; ++kc) {
        h8 bf0 = *(const h8*)&wp[(((w * 2 + 0) * 4 + kc) * 64 + lane) * 8];
        h8 bf1 = *(const h8*)&wp[(((w * 2 + 1) * 4 + kc) * 64 + lane) * 8];
        int co = ((kc * 4 + quad) ^ (cl & 7)) << 3;
        h8 af[4];
#pragma unroll
        for (int rt = 0; rt < 4; ++rt)
            af[rt] = *(const h8*)&X[(rt * 16 + cl) * 128 + co];
#pragma unroll
        for (int rt = 0; rt < 4; ++rt) {
            acc[rt][0] = __builtin_amdgcn_mfma_f32_16x16x32_f16(af[rt], bf0, acc[rt][0], 0, 0, 0);
            acc[rt][1] = __builtin_amdgcn_mfma_f32_16x16x32_f16(af[rt], bf1, acc[rt][1], 0, 0, 0);
        }
    }
}

// ---------------------------------------------------------------------------
// Kernels
// ---------------------------------------------------------------------------

// mlp1 (round-10 proven): 16-row tiles (256 compute blocks) + fused prep
// (blocks 256..336: zero sums2+cvec, pack w2/w4 layer-2 weights to fp16
// frag layout). Slot stats -> 256 slots in the h3 arena.
__global__ __launch_bounds__(256) void k_mlp1p(const float* __restrict__ x,
                                               const float* __restrict__ w1,
                                               const float* __restrict__ b1,
                                               const float* __restrict__ w2,
                                               const float* __restrict__ b2,
                                               float* __restrict__ h1,
                                               float* __restrict__ slots,
                                               float* __restrict__ sums2,
                                               float* __restrict__ cvec,
                                               const float* __restrict__ w2src,
                                               _Float16* __restrict__ w2p,
                                               const float* __restrict__ w4src,
                                               _Float16* __restrict__ w4p) {
    __shared__ float Xs[16 * 44];
    __shared__ float As[4224];  // gemm tile uses 16*132=2112; stats tail uses 4096
    int tid = threadIdx.x;
    int blk = blockIdx.x;
    if (blk >= 256) {
        if (blk < 321) {  // zeroing (65 blocks)
            int i = (blk - 256) * 256 + tid;
            if (i < 16384) sums2[i] = 0.f;
            else if (i < 16512) cvec[i - 16384] = 0.f;
        } else {  // weight packing (8 + 8 blocks)
            int second = blk >= 329;
            const float* src = second ? w4src : w2src;
            _Float16* wp = second ? w4p : w2p;
            int flat = (blk - (second ? 329 : 321)) * 256 + tid;  // 0..2047
            int g = flat >> 6, L = flat & 63;
            int ct = g >> 2, kc = g & 3;
            int nn = ct * 16 + (L & 15), k0 = kc * 32 + (L >> 4) * 8;
            h8 v;
#pragma unroll
            for (int j = 0; j < 8; ++j) v[j] = (_Float16)src[(k0 + j) * 128 + nn];
            *(h8*)&wp[flat * 8] = v;
        }
        return;
    }
    int tx = tid & 15, ty = tid >> 4;
    int r0 = blk * 16;
    for (int idx = tid; idx < 16 * 40; idx += 256) {
        int r = idx / 40, k = idx - r * 40;
        int rr = r0 + r, b = rr >> 6, n = rr & 63, t = k >> 2, d = k & 3;
        Xs[r * 44 + k] = x[((b * 10 + t) * 64 + n) * 4 + d];
    }
    __syncthreads();
    float acc[8] = {};
    gemm16_globalW(Xs, 44, w1, 40, acc, tx, ty);
    float vals[8];
    bias_elu16(acc, b1, vals, tx);
    int ca = 4 * tx, cb = 64 + 4 * tx;
#pragma unroll
    for (int u = 0; u < 4; ++u) {
        As[ty * 132 + ca + u] = vals[u];
        As[ty * 132 + cb + u] = vals[u + 4];
    }
    __syncthreads();
    float acc2[8] = {};
    gemm16_globalW(As, 132, w2, 128, acc2, tx, ty);
    float vals2[8];
    bias_elu16(acc2, b2, vals2, tx);
    int r = r0 + ty;
    *(float4*)(h1 + r * 128 + 4 * tx) = make_float4(vals2[0], vals2[1], vals2[2], vals2[3]);
    *(float4*)(h1 + r * 128 + 64 + 4 * tx) = make_float4(vals2[4], vals2[5], vals2[6], vals2[7]);
    stats_tail16_store(vals2, As, slots + blk * 256, tid, tx, ty);
}

// P/Q precompute with fused BN-coef derivation from nslots plain-store slots.
// 16-row tiles, grid 512 (2 blocks/CU). Optionally zeroes zero4[0:16384)
// distributed across the 512 blocks (pq4).
__global__ __launch_bounds__(256) void k_pqf(const float* __restrict__ h,
                                             const float* __restrict__ slots,
                                             int nslots,
                                             const float* __restrict__ g,
                                             const float* __restrict__ beta,
                                             const float* __restrict__ w,
                                             float* __restrict__ P, float* __restrict__ Q,
                                             float* __restrict__ zero4) {
    __shared__ float Cf[256];
    __shared__ float As[16 * 132];
    int tid = threadIdx.x, tx = tid & 15, ty = tid >> 4;
    int half = blockIdx.x >> 8;
    int r0 = (blockIdx.x & 255) * 16;
    if (zero4 && tid < 32) zero4[blockIdx.x * 32 + tid] = 0.f;
    if (tid < 128) {
        int c = tid;
        float s = 0.f, q = 0.f;
#pragma unroll 8
        for (int t = 0; t < nslots; ++t) {
            s += slots[t * 256 + c];
            q += slots[t * 256 + 128 + c];
        }
        float mean = s * (1.f / 4096.f);
        float var = q * (1.f / 4096.f) - mean * mean;
        float a = g[c] * rsqrtf(var + BN_EPS);
        Cf[c] = a;
        Cf[128 + c] = beta[c] - mean * a;
    }
    __syncthreads();
    const float* Wg = w + half * 128 * 128;
    float* out = half ? Q : P;
    const float4* h4p = (const float4*)h;
#pragma unroll
    for (int i = 0; i < 2; ++i) {
        int f4 = tid + i * 256;
        int r = f4 >> 5, c4 = f4 & 31;
        float4 hv = h4p[(r0 + r) * 32 + c4];
        int cb = c4 * 4;
        float4 v;
        v.x = Cf[cb] * hv.x + Cf[128 + cb];
        v.y = Cf[cb + 1] * hv.y + Cf[128 + cb + 1];
        v.z = Cf[cb + 2] * hv.z + Cf[128 + cb + 2];
        v.w = Cf[cb + 3] * hv.w + Cf[128 + cb + 3];
        *(float4*)(As + r * 132 + c4 * 4) = v;
    }
    __syncthreads();
    float acc[8] = {};
    gemm16_globalW(As, 132, Wg, 128, acc, tx, ty);
    int r = r0 + ty;
    *(float4*)(out + r * 128 + 4 * tx) = make_float4(acc[0], acc[1], acc[2], acc[3]);
    *(float4*)(out + r * 128 + 64 + 4 * tx) = make_float4(acc[4], acc[5], acc[6], acc[7]);
}

// Recv-major fused mlp2 + edge2node + h2 materialization (round-5 proven:
// coalesced stage into swizzled row-major LDS, gemm1_swz, reordered h2 write).
__global__ __launch_bounds__(256, 6) void k_mlp2agg(const float* __restrict__ P2,
                                                    const float* __restrict__ Q2,
                                                    const float* __restrict__ b1,
                                                    const _Float16* __restrict__ w2p,
                                                    const float* __restrict__ b2,
                                                    float* __restrict__ aggraw,
                                                    _Float16* __restrict__ h2,
                                                    float* __restrict__ st) {
    __shared__ __align__(16) _Float16 Afr[9216];
    int tid = threadIdx.x;
    int lane = tid & 63, w = tid >> 6, cl = lane & 15, quad = lane >> 4;
    int b = blockIdx.x >> 6, n0 = blockIdx.x & 63;
    float* stc = st + n0 * 256;
    // --- coalesced stage into row-major swizzled tile X[64][128] fp16 ---
    {
        int c4 = tid & 31;    // float4 column 0..31
        int rsub = tid >> 5;  // 0..7
        const float4* Qr = (const float4*)(Q2 + (b * 64 + n0) * 128);
        const float4* B1 = (const float4*)b1;
        float4 qv = Qr[c4];
        float4 bv = B1[c4];
        float qbx = qv.x + bv.x, qby = qv.y + bv.y;
        float qbz = qv.z + bv.z, qbw = qv.w + bv.w;
        const float4* P4p = (const float4*)(P2 + (size_t)b * 64 * 128);
#pragma unroll
        for (int it = 0; it < 8; ++it) {
            int r = it * 8 + rsub;
            int s0 = (r < 63) ? (r + (r >= n0 ? 1 : 0)) : n0;  // row 63: dummy
            float4 p = P4p[s0 * 32 + c4];
            h4v v;
            v[0] = (_Float16)elu_f(p.x + qbx);
            v[1] = (_Float16)elu_f(p.y + qby);
            v[2] = (_Float16)elu_f(p.z + qbz);
            v[3] = (_Float16)elu_f(p.w + qbw);
            int off = r * 128 + ((((c4 >> 1) ^ (r & 7)) << 3) | ((c4 & 1) << 2));
            *(h4v*)&Afr[off] = v;
        }
    }
    __syncthreads();
    f4v acc[4][2];
#pragma unroll
    for (int rt = 0; rt < 4; ++rt)
#pragma unroll
        for (int c = 0; c < 2; ++c)
            acc[rt][c] = (f4v){0.f, 0.f, 0.f, 0.f};
    gemm1_swz(Afr, w2p, acc, lane, w, cl, quad);
    float v0[2][4][4];
#pragma unroll
    for (int ctl = 0; ctl < 2; ++ctl) {
        int col = (w * 2 + ctl) * 16 + cl;
        float bias = b2[col];
        float a0 = 0.f, sq = 0.f;
#pragma unroll
        for (int rt = 0; rt < 4; ++rt)
#pragma unroll
            for (int i = 0; i < 4; ++i) {
                int row = rt * 16 + quad * 4 + i;
                float va = elu_f(acc[rt][ctl][i] + bias);
                if (row == 63) va = 0.f;
                v0[ctl][rt][i] = va;
                a0 += va;
                sq += va * va;
            }
        a0 += __shfl_xor(a0, 16);
        sq += __shfl_xor(sq, 16);
        a0 += __shfl_xor(a0, 32);
        sq += __shfl_xor(sq, 32);
        if (quad == 0) {
            aggraw[(b * 64 + n0) * 128 + col] = a0;
            atomicAdd(stc + col, a0);
            atomicAdd(stc + 128 + col, sq);
        }
    }
    __syncthreads();
    unsigned short* T0 = (unsigned short*)Afr;
#pragma unroll
    for (int ctl = 0; ctl < 2; ++ctl) {
        int col = (w * 2 + ctl) * 16 + cl;
#pragma unroll
        for (int rt = 0; rt < 4; ++rt)
#pragma unroll
            for (int i = 0; i < 4; ++i) {
                int row = rt * 16 + quad * 4 + i;
                _Float16 ha = (_Float16)v0[ctl][rt][i];
                T0[row * 144 + col] = *(unsigned short*)&ha;
            }
    }
    __syncthreads();
    {
        int rr = tid >> 2, cq = tid & 3;
        if (rr < 63) {
            int s0 = rr + (rr >= n0 ? 1 : 0);
            int e0 = s0 * 63 + (s0 > n0 ? n0 : n0 - 1);
            unsigned short* d0 = (unsigned short*)h2 + ((size_t)b * 4032 + e0) * 128;
#pragma unroll
            for (int i = 0; i < 4; ++i) {
                int off = i * 32 + cq * 8;  // row's 4 lanes contiguous (64B)
                *(uint4*)(d0 + off) = *(uint4*)&T0[rr * 144 + off];
            }
        }
    }
}

// fused BN2-finalize + wcprep: block k derives coef2[k] pair from the 64-slot
// atomic arena, writes it (for mlp3), then scales W4_1[256+k][:] into wcp and
// accumulates cvec.
__global__ __launch_bounds__(128) void k_wcfin(const float* __restrict__ sums2,
                                               const float* __restrict__ g2,
                                               const float* __restrict__ be2,
                                               const float* __restrict__ w41,
                                               _Float16* __restrict__ wcp,
                                               float* __restrict__ cvec,
                                               float* __restrict__ coef2) {
    __shared__ float red[128];
    __shared__ float pr[2];
    int k = blockIdx.x, c = threadIdx.x;  // 128 threads
    red[c] = (c < 64) ? sums2[c * 256 + k] : sums2[(c - 64) * 256 + 128 + k];
    __syncthreads();
    if (c == 0) {
        float s = 0.f, q = 0.f;
#pragma unroll 8
        for (int t = 0; t < 64; ++t) {
            s += red[t];
            q += red[64 + t];
        }
        float mean = s * (1.f / 258048.f);
        float var = q * (1.f / 258048.f) - mean * mean;
        float a = g2[k] * rsqrtf(var + BN_EPS);
        pr[0] = a;
        pr[1] = be2[k] - mean * a;
        coef2[k] = a;
        coef2[128 + k] = pr[1];
    }
    __syncthreads();
    float a2k = pr[0], sh2k = pr[1];
    float wv = w41[(256 + k) * 128 + c];
    int g = (c >> 4) * 4 + (k >> 5);
    int L = ((k >> 3) & 3) * 16 + (c & 15);
    int j = k & 7;
    wcp[(g * 64 + L) * 8 + j] = (_Float16)(a2k * wv);
    atomicAdd(&cvec[c], sh2k * wv);
}

// mlp3 (round-9 proven): 16-row tiles, 256 blocks, 256 stat slots.
__global__ __launch_bounds__(256) void k_mlp3(const float* __restrict__ raw,
                                              const float* __restrict__ coef2,
                                              const float* __restrict__ w1,
                                              const float* __restrict__ b1,
                                              const float* __restrict__ w2,
                                              const float* __restrict__ b2,
                                              float* __restrict__ h3,
                                              float* __restrict__ slots) {
    __shared__ float As[4224];  // staging/GEMM uses 16*132=2112; stats tail uses 4096
    int tid = threadIdx.x, tx = tid & 15, ty = tid >> 4;
    int r0 = blockIdx.x * 16;
    const float4* in4 = (const float4*)raw;
    const float4* av = (const float4*)coef2;
    const float4* cv = (const float4*)(coef2 + 128);
    const float inv63 = 1.f / 63.f;
#pragma unroll
    for (int i = 0; i < 2; ++i) {
        int f4 = tid + i * 256;
        int r = f4 >> 5, c4 = f4 & 31;
        float4 hv = in4[(r0 + r) * 32 + c4];
        float4 a = av[c4], c = cv[c4];
        float4 v;
        v.x = a.x * hv.x * inv63 + c.x;
        v.y = a.y * hv.y * inv63 + c.y;
        v.z = a.z * hv.z * inv63 + c.z;
        v.w = a.w * hv.w * inv63 + c.w;
        *(float4*)(As + r * 132 + c4 * 4) = v;
    }
    __syncthreads();
    float acc[8] = {};
    gemm16_globalW(As, 132, w1, 128, acc, tx, ty);
    float vals[8];
    bias_elu16(acc, b1, vals, tx);
    __syncthreads();
    int ca = 4 * tx, cb = 64 + 4 * tx;
#pragma unroll
    for (int u = 0; u < 4; ++u) {
        As[ty * 132 + ca + u] = vals[u];
        As[ty * 132 + cb + u] = vals[u + 4];
    }
    __syncthreads();
    float acc2[8] = {};
    gemm16_globalW(As, 132, w2, 128, acc2, tx, ty);
    float vals2[8];
    bias_elu16(acc2, b2, vals2, tx);
    int r = r0 + ty;
    *(float4*)(h3 + r * 128 + 4 * tx) = make_float4(vals2[0], vals2[1], vals2[2], vals2[3]);
    *(float4*)(h3 + r * 128 + 64 + 4 * tx) = make_float4(vals2[4], vals2[5], vals2[6], vals2[7]);
    stats_tail16_store(vals2, As, slots + blockIdx.x * 256, tid, tx, ty);
}

// mlp4 edge kernel — ROUND-9 PROVEN VERSION (48.7 µs, VGPR 40, no spills).
// Gather sits between gemm1 and tile2; do NOT hoist it (r10: spilled, +90 MB
// scratch traffic). Bounds (256,6); do NOT raise (r6: spilled).
__global__ __launch_bounds__(256, 6) void k_mlp4r3(const _Float16* __restrict__ h2,
                                                   const float* __restrict__ P4,
                                                   const float* __restrict__ Q4,
                                                   const _Float16* __restrict__ wcp,
                                                   const float* __restrict__ cvec,
                                                   const float* __restrict__ b1,
                                                   const _Float16* __restrict__ w4p2,
                                                   const float* __restrict__ b2,
                                                   unsigned short* __restrict__ h4,
                                                   float* __restrict__ st) {
    __shared__ __align__(16) _Float16 Afr[8192];
    int tid = threadIdx.x;
    int lane = tid & 63, w = tid >> 6, cl = lane & 15, quad = lane >> 4;
    unsigned t0 = blockIdx.x;
    unsigned b0 = t0 / 63;
    unsigned e00 = (t0 - b0 * 63) * 64;
    float* stc = st + (blockIdx.x & 63) * 256;
    {
        const _Float16* hb = h2 + (size_t)t0 * 8192;
#pragma unroll
        for (int i = 0; i < 4; ++i) {
            int u = tid + i * 256;
            int r = u >> 4, c = u & 15;
            h8 v = *(const h8*)&hb[r * 128 + c * 8];
            *(h8*)&Afr[r * 128 + ((c ^ (r & 7)) << 3)] = v;
        }
    }
    __syncthreads();
    f4v acc[4][2];
#pragma unroll
    for (int rt = 0; rt < 4; ++rt)
#pragma unroll
        for (int c = 0; c < 2; ++c)
            acc[rt][c] = (f4v){0.f, 0.f, 0.f, 0.f};
    gemm1_swz(Afr, wcp, acc, lane, w, cl, quad);
    float v0[4][2][4];
    {
        int col0 = w * 32 + cl, col1 = col0 + 16;
        float base0 = b1[col0] + cvec[col0];
        float base1 = b1[col1] + cvec[col1];
        unsigned sA0 = e00 / 63;
        unsigned baseE0 = sA0 * 63;
        unsigned eB0 = baseE0 + 63;
        unsigned sB0 = sA0 < 63u ? sA0 + 1u : sA0;
        const float* PA0 = P4 + (b0 * 64 + sA0) * 128;
        const float* PB0 = P4 + (b0 * 64 + sB0) * 128;
        float pA0c0 = PA0[col0], pA0c1 = PA0[col1];
        float pB0c0 = PB0[col0], pB0c1 = PB0[col1];
        const float* Qb0 = Q4 + (size_t)b0 * 8192;
#pragma unroll
        for (int rt = 0; rt < 4; ++rt)
#pragma unroll
            for (int i = 0; i < 4; ++i) {
                int rr = rt * 16 + quad * 4 + i;
                unsigned e = e00 + rr;
                bool hi = e >= eB0;
                unsigned s = hi ? sB0 : sA0;
                unsigned jj = e - (hi ? eB0 : baseE0);
                unsigned rv = jj + (jj >= s ? 1u : 0u);
                const float* Qr = Qb0 + rv * 128;
                float p0 = hi ? pB0c0 : pA0c0, p1 = hi ? pB0c1 : pA0c1;
                v0[rt][0][i] = elu_f(acc[rt][0][i] + p0 + Qr[col0] + base0);
                v0[rt][1][i] = elu_f(acc[rt][1][i] + p1 + Qr[col1] + base1);
            }
    }
    __syncthreads();
    // tile2: write intermediate X2[row][col] into the same swizzled layout
    {
        int colb0 = w * 32 + cl, colb1 = colb0 + 16;
        int cc0 = colb0 >> 3, cj0 = colb0 & 7;
        int cc1 = colb1 >> 3, cj1 = colb1 & 7;
#pragma unroll
        for (int rt = 0; rt < 4; ++rt)
#pragma unroll
            for (int i = 0; i < 4; ++i) {
                int row = rt * 16 + quad * 4 + i;
                int rx = row & 7;
                Afr[row * 128 + (((cc0 ^ rx) << 3) | cj0)] = (_Float16)v0[rt][0][i];
                Afr[row * 128 + (((cc1 ^ rx) << 3) | cj1)] = (_Float16)v0[rt][1][i];
            }
    }
    __syncthreads();
#pragma unroll
    for (int rt = 0; rt < 4; ++rt)
#pragma unroll
        for (int c = 0; c < 2; ++c)
            acc[rt][c] = (f4v){0.f, 0.f, 0.f, 0.f};
    gemm1_swz(Afr, w4p2, acc, lane, w, cl, quad);
#pragma unroll
    for (int ctl = 0; ctl < 2; ++ctl) {
        int col = (w * 2 + ctl) * 16 + cl;
        float bias = b2[col];
        float s1 = 0.f, s2 = 0.f;
#pragma unroll
        for (int rt = 0; rt < 4; ++rt)
#pragma unroll
            for (int i = 0; i < 4; ++i) {
                float va = elu_f(acc[rt][ctl][i] + bias);
                v0[rt][ctl][i] = va;
                s1 += va;
                s2 += va * va;
            }
        s1 += __shfl_xor(s1, 16);
        s2 += __shfl_xor(s2, 16);
        s1 += __shfl_xor(s1, 32);
        s2 += __shfl_xor(s2, 32);
        if (quad == 0) {
            atomicAdd(stc + col, s1);
            atomicAdd(stc + 128 + col, s2);
        }
    }
    // direct C-layout store: idx = ((cg*4+rt)*4+quad)*64 + cl*4 + i
    {
        unsigned short* o0 = h4 + (size_t)t0 * 8192;
#pragma unroll
        for (int ctl = 0; ctl < 2; ++ctl) {
            int cg = w * 2 + ctl;
#pragma unroll
            for (int rt = 0; rt < 4; ++rt) {
                int idx = ((cg * 4 + rt) * 4 + quad) * 64 + cl * 4;
                h4v a;
#pragma unroll
                for (int i = 0; i < 4; ++i) a[i] = (_Float16)v0[rt][ctl][i];
                *(h4v*)(o0 + idx) = a;
            }
        }
    }
}

// fused BN4-finalize + fc output, reading h4 in C-layout. BN is folded into
// the fc weights: u_k[c] = a[c]*w[c][k]; out = h.u_k + C_k with
// C_k = sum_c sh[c]*w[c][k] + fcb[k].
__global__ __launch_bounds__(256) void k_outf(const unsigned short* __restrict__ h4,
                                              const float* __restrict__ sums4,
                                              const float* __restrict__ g4,
                                              const float* __restrict__ be4,
                                              const float* __restrict__ fcw,
                                              const float* __restrict__ fcb,
                                              float* __restrict__ out) {
    __shared__ float U0[128];
    __shared__ float U1[128];
    __shared__ float Cp[4];
    int tid = threadIdx.x;
    if (tid < 128) {
        int c = tid;
        float s = 0.f, q = 0.f;
#pragma unroll 8
        for (int t = 0; t < 64; ++t) {
            s += sums4[t * 256 + c];
            q += sums4[t * 256 + 128 + c];
        }
        float mean = s * (1.f / 258048.f);
        float var = q * (1.f / 258048.f) - mean * mean;
        float a = g4[c] * rsqrtf(var + BN_EPS);
        float sh = be4[c] - mean * a;
        float w0 = fcw[2 * c], w1 = fcw[2 * c + 1];
        U0[c] = a * w0;
        U1[c] = a * w1;
        float p0 = sh * w0, p1 = sh * w1;
#pragma unroll
        for (int off = 1; off < 64; off <<= 1) {
            p0 += __shfl_xor(p0, off);
            p1 += __shfl_xor(p1, off);
        }
        if ((tid & 63) == 0) {
            Cp[(tid >> 6) * 2] = p0;
            Cp[(tid >> 6) * 2 + 1] = p1;
        }
    }
    __syncthreads();
    float C0 = Cp[0] + Cp[2] + fcb[0];
    float C1 = Cp[1] + Cp[3] + fcb[1];
    int lane = tid & 63, w = tid >> 6;
    int quad = lane >> 4, cl = lane & 15;
    float u0r[8], u1r[8];
#pragma unroll
    for (int cg = 0; cg < 8; ++cg) {
        u0r[cg] = U0[cg * 16 + cl];
        u1r[cg] = U1[cg * 16 + cl];
    }
    size_t tile = (size_t)blockIdx.x * 4 + w;
    const unsigned short* hb = h4 + tile * 8192;
#pragma unroll
    for (int rt = 0; rt < 4; ++rt) {
        float s00 = 0.f, s01 = 0.f, s02 = 0.f, s03 = 0.f;
        float s10 = 0.f, s11 = 0.f, s12 = 0.f, s13 = 0.f;
#pragma unroll
        for (int cg = 0; cg < 8; ++cg) {
            h4v hv = *(const h4v*)(hb + ((cg * 4 + rt) * 4 + quad) * 64 + cl * 4);
            float u0 = u0r[cg], u1 = u1r[cg];
            float x0 = (float)hv[0], x1 = (float)hv[1];
            float x2 = (float)hv[2], x3 = (float)hv[3];
            s00 = fmaf(x0, u0, s00); s01 = fmaf(x1, u0, s01);
            s02 = fmaf(x2, u0, s02); s03 = fmaf(x3, u0, s03);
            s10 = fmaf(x0, u1, s10); s11 = fmaf(x1, u1, s11);
            s12 = fmaf(x2, u1, s12); s13 = fmaf(x3, u1, s13);
        }
#pragma unroll
        for (int off = 1; off < 16; off <<= 1) {
            s00 += __shfl_xor(s00, off); s01 += __shfl_xor(s01, off);
            s02 += __shfl_xor(s02, off); s03 += __shfl_xor(s03, off);
            s10 += __shfl_xor(s10, off); s11 += __shfl_xor(s11, off);
            s12 += __shfl_xor(s12, off); s13 += __shfl_xor(s13, off);
        }
        if (cl == 0) {
            size_t R = tile * 64 + rt * 16 + quad * 4;
            *(float4*)(out + R * 2) =
                make_float4(s00 + C0, s10 + C1, s01 + C0, s11 + C1);
            *(float4*)(out + R * 2 + 4) =
                make_float4(s02 + C0, s12 + C1, s03 + C0, s13 + C1);
        }
    }
}

// ---------------------------------------------------------------------------

extern "C" void kernel_launch(void* const* d_in, const int* in_sizes, int n_in,
                              void* d_out, int out_size, void* d_ws, size_t ws_size,
                              hipStream_t stream) {
    const float* x = (const float*)d_in[0];
    const float* m1_w1 = (const float*)d_in[1];
    const float* m1_b1 = (const float*)d_in[2];
    const float* m1_w2 = (const float*)d_in[3];
    const float* m1_b2 = (const float*)d_in[4];
    const float* m1_g = (const float*)d_in[5];
    const float* m1_be = (const float*)d_in[6];
    const float* m2_w1 = (const float*)d_in[7];
    const float* m2_b1 = (const float*)d_in[8];
    const float* m2_w2 = (const float*)d_in[9];
    const float* m2_b2 = (const float*)d_in[10];
    const float* m2_g = (const float*)d_in[11];
    const float* m2_be = (const float*)d_in[12];
    const float* m3_w1 = (const float*)d_in[13];
    const float* m3_b1 = (const float*)d_in[14];
    const float* m3_w2 = (const float*)d_in[15];
    const float* m3_b2 = (const float*)d_in[16];
    const float* m3_g = (const float*)d_in[17];
    const float* m3_be = (const float*)d_in[18];
    const float* m4_w1 = (const float*)d_in[19];
    const float* m4_b1 = (const float*)d_in[20];
    const float* m4_w2 = (const float*)d_in[21];
    const float* m4_b2 = (const float*)d_in[22];
    const float* m4_g = (const float*)d_in[23];
    const float* m4_be = (const float*)d_in[24];
    const float* fc_w = (const float*)d_in[25];
    const float* fc_b = (const float*)d_in[26];
    float* out = (float*)d_out;

    float* W = (float*)d_ws;
    float* coef2 = W + OFF_COEF;
    float* cvec = W + OFF_CVEC;
    float* h1 = W + OFF_H1;            // aliased: aggraw; sums4 = h1[0:16384)
    float* aggraw = h1;
    float* sums4 = h1;
    float* P2 = W + OFF_P2;            // sums3 slots = P2[0:65536) (P2 dead then)
    float* sums3 = P2;
    float* Q2 = W + OFF_Q2;
    float* h3 = W + OFF_H3;            // sums1 slots = h3[0:65536) (h3 written later)
    float* sums1 = h3;
    float* P4 = W + OFF_P4;            // sums2 arena = P4[0:16384)
    float* sums2 = P4;
    float* Q4 = W + OFF_Q4;
    _Float16* w2p2 = (_Float16*)(W + OFF_W2P);
    _Float16* w4p2 = (_Float16*)(W + OFF_W4P);
    _Float16* wcp = (_Float16*)(W + OFF_WCP);
    _Float16* h2f = (_Float16*)(W + OFF_H4B);             // h2 (fp16), then
    unsigned short* h4b = (unsigned short*)(W + OFF_H4B); // h4 (fp16, C-layout) in place

    if (ws_size < WS_BYTES) return;  // safe-fail diagnostic (no OOB fault)

    k_mlp1p<<<337, 256, 0, stream>>>(x, m1_w1, m1_b1, m1_w2, m1_b2, h1, sums1,
                                     sums2, cvec, m2_w2, w2p2, m4_w2, w4p2);
    k_pqf<<<512, 256, 0, stream>>>(h1, sums1, 256, m1_g, m1_be, m2_w1, P2, Q2, nullptr);
    k_mlp2agg<<<4096, 256, 0, stream>>>(P2, Q2, m2_b1, w2p2, m2_b2, aggraw, h2f, sums2);
    k_wcfin<<<128, 128, 0, stream>>>(sums2, m2_g, m2_be, m4_w1, wcp, cvec, coef2);
    k_mlp3<<<256, 256, 0, stream>>>(aggraw, coef2, m3_w1, m3_b1, m3_w2, m3_b2, h3, sums3);
    k_pqf<<<512, 256, 0, stream>>>(h3, sums3, 256, m3_g, m3_be, m4_w1, P4, Q4, sums4);
    k_mlp4r3<<<4032, 256, 0, stream>>>(h2f, P4, Q4, wcp, cvec, m4_b1, w4p2, m4_b2,
                                       h4b, sums4);
    k_outf<<<1008, 256, 0, stream>>>(h4b, sums4, m4_g, m4_be, fc_w, fc_b, out);
}

// Round 12
// 281.662 us; speedup vs baseline: 1.0742x; 1.0361x over previous
//
#include <hip/hip_runtime.h>

#define BN_EPS 1e-5f

using h8 = __attribute__((ext_vector_type(8))) _Float16;
using h4v = __attribute__((ext_vector_type(4))) _Float16;
using f4v = __attribute__((ext_vector_type(4))) float;

// workspace float offsets (proven layout). Slot/arena aliases:
//   sums1 (mlp1 slots, 128x256, plain stores)  = H3[0:32768)   (h3 written later)
//   sums3 (mlp3 slots, 256x256, plain stores)  = P2[0:65536)   (P2 dead then)
//   sums2 (mlp2 arena, 64x256, atomics)        = P4[0:16384)
//   sums4 (mlp4 arena, 64x256, atomics)        = H1[0:16384)   (zeroed in pq4)
// h4 is stored in MFMA C-layout per 64-row tile (8192 u16/tile):
//   idx(tile,row,col) = tile*8192 + ((cg*4+rt)*4+quad)*64 + cl*4 + i
//   where rt=(row>>4)&3, quad=(row>>2)&3, i=row&3, cg=col>>4, cl=col&15.
// REGALLOC RULE (proven r6 & r10): k_mlp4r3 cannot hold ANY extra live state
// across its GEMMs — both attempts spilled (+90 MB scratch traffic). The
// gather-after-gemm1 ordering and (256,6) bounds are load-bearing.
// GRID RULE (proven r11): mlp1p stays 32-row — its TWO weight-bound K-loops
// stream full W1+W2 per block, so halving tiles doubles weight traffic.
#define OFF_COEF 0        // coef2 only: a @ [0:128), shift @ [128:256)
#define OFF_CVEC 1024     // 128
#define OFF_H1 4096       // 4096x128 (aliased: aggraw; first 16384 = sums4)
#define OFF_P2 528384
#define OFF_Q2 1052672
#define OFF_H3 1576960
#define OFF_P4 2101248
#define OFF_Q4 2625536
#define OFF_W2P 3149824   // 16384 fp16 = 8192 floats each
#define OFF_W4P 3158016
#define OFF_WCP 3166208
#define OFF_H4B 3174400   // 258048x128 fp16: h2 then h4 in place
#define WS_BYTES 78757888ull

__device__ __forceinline__ float elu_f(float x) {
    return x > 0.f ? x : __expf(x) - 1.f;
}

// ---------------------------------------------------------------------------
// fp32 tile GEMM helpers. 32-row (mlp1p) and 16-row (pqf/mlp3) variants.
// ---------------------------------------------------------------------------

__device__ __forceinline__ void gemm32_globalW(const float* As, int lda,
                                               const float* __restrict__ Wg, int K,
                                               float acc[2][8], int tx, int ty) {
    const float4* Wg4 = (const float4*)Wg;
#pragma unroll 4
    for (int k = 0; k < K; ++k) {
        float a0 = As[ty * lda + k];
        float a1 = As[(ty + 16) * lda + k];
        float4 wa = Wg4[k * 32 + tx];
        float4 wb = Wg4[k * 32 + 16 + tx];
        const float wv[8] = {wa.x, wa.y, wa.z, wa.w, wb.x, wb.y, wb.z, wb.w};
#pragma unroll
        for (int u = 0; u < 8; ++u) {
            acc[0][u] = fmaf(a0, wv[u], acc[0][u]);
            acc[1][u] = fmaf(a1, wv[u], acc[1][u]);
        }
    }
}

__device__ __forceinline__ void gemm16_globalW(const float* As, int lda,
                                               const float* __restrict__ Wg, int K,
                                               float acc[8], int tx, int ty) {
    const float4* Wg4 = (const float4*)Wg;
#pragma unroll 4
    for (int k = 0; k < K; ++k) {
        float a0 = As[ty * lda + k];
        float4 wa = Wg4[k * 32 + tx];
        float4 wb = Wg4[k * 32 + 16 + tx];
        acc[0] = fmaf(a0, wa.x, acc[0]);
        acc[1] = fmaf(a0, wa.y, acc[1]);
        acc[2] = fmaf(a0, wa.z, acc[2]);
        acc[3] = fmaf(a0, wa.w, acc[3]);
        acc[4] = fmaf(a0, wb.x, acc[4]);
        acc[5] = fmaf(a0, wb.y, acc[5]);
        acc[6] = fmaf(a0, wb.z, acc[6]);
        acc[7] = fmaf(a0, wb.w, acc[7]);
    }
}

__device__ __forceinline__ void bias_elu32(const float acc[2][8],
                                           const float* __restrict__ bias,
                                           float vals[2][8], int tx) {
    int ca = 4 * tx, cb = 64 + 4 * tx;
    float bv[8] = {bias[ca], bias[ca + 1], bias[ca + 2], bias[ca + 3],
                   bias[cb], bias[cb + 1], bias[cb + 2], bias[cb + 3]};
#pragma unroll
    for (int j = 0; j < 2; ++j)
#pragma unroll
        for (int u = 0; u < 8; ++u)
            vals[j][u] = elu_f(acc[j][u] + bv[u]);
}

__device__ __forceinline__ void bias_elu16(const float acc[8],
                                           const float* __restrict__ bias,
                                           float vals[8], int tx) {
    int ca = 4 * tx, cb = 64 + 4 * tx;
    float bv[8] = {bias[ca], bias[ca + 1], bias[ca + 2], bias[ca + 3],
                   bias[cb], bias[cb + 1], bias[cb + 2], bias[cb + 3]};
#pragma unroll
    for (int u = 0; u < 8; ++u)
        vals[u] = elu_f(acc[u] + bv[u]);
}

__device__ __forceinline__ void store_tile32(float* __restrict__ out, int row0,
                                             const float vals[2][8], int tx, int ty) {
#pragma unroll
    for (int j = 0; j < 2; ++j) {
        int r = row0 + ty + 16 * j;
        *(float4*)(out + r * 128 + 4 * tx) =
            make_float4(vals[j][0], vals[j][1], vals[j][2], vals[j][3]);
        *(float4*)(out + r * 128 + 64 + 4 * tx) =
            make_float4(vals[j][4], vals[j][5], vals[j][6], vals[j][7]);
    }
}

// 32-row stats -> per-block slot (plain stores; no zero-init needed).
__device__ __forceinline__ void stats_tail32_store(const float vals[2][8], float* red,
                                                   float* __restrict__ slot, int tid,
                                                   int tx, int ty) {
    float ls[8], lq[8];
#pragma unroll
    for (int u = 0; u < 8; ++u) {
        ls[u] = vals[0][u] + vals[1][u];
        lq[u] = vals[0][u] * vals[0][u] + vals[1][u] * vals[1][u];
    }
    __syncthreads();
    int ca = 4 * tx, cb = 64 + 4 * tx;
#pragma unroll
    for (int u = 0; u < 4; ++u) {
        red[ty * 128 + ca + u] = ls[u];
        red[2048 + ty * 128 + ca + u] = lq[u];
        red[ty * 128 + cb + u] = ls[u + 4];
        red[2048 + ty * 128 + cb + u] = lq[u + 4];
    }
    __syncthreads();
    if (tid < 128) {
        float s = 0.f, q = 0.f;
#pragma unroll
        for (int t = 0; t < 16; ++t) {
            s += red[t * 128 + tid];
            q += red[2048 + t * 128 + tid];
        }
        slot[tid] = s;
        slot[128 + tid] = q;
    }
}

// 16-row stats -> per-block slot.
__device__ __forceinline__ void stats_tail16_store(const float vals[8], float* red,
                                                   float* __restrict__ slot, int tid,
                                                   int tx, int ty) {
    __syncthreads();
    int ca = 4 * tx, cb = 64 + 4 * tx;
#pragma unroll
    for (int u = 0; u < 4; ++u) {
        red[ty * 128 + ca + u] = vals[u];
        red[2048 + ty * 128 + ca + u] = vals[u] * vals[u];
        red[ty * 128 + cb + u] = vals[u + 4];
        red[2048 + ty * 128 + cb + u] = vals[u + 4] * vals[u + 4];
    }
    __syncthreads();
    if (tid < 128) {
        float s = 0.f, q = 0.f;
#pragma unroll
        for (int t = 0; t < 16; ++t) {
            s += red[t * 128 + tid];
            q += red[2048 + t * 128 + tid];
        }
        slot[tid] = s;
        slot[128 + tid] = q;
    }
}

// ---------------------------------------------------------------------------
// MFMA helpers (proven).
// ---------------------------------------------------------------------------

// single-tile MFMA GEMM: A from row-major XOR-swizzled LDS tile [64][128] fp16
// (LDS row r holds global 16B-chunk c at position c^(r&7); verified r2/r5/r7).
__device__ __forceinline__ void gemm1_swz(const _Float16* X,
                                          const _Float16* __restrict__ wp,
                                          f4v acc[4][2], int lane, int w,
                                          int cl, int quad) {
#pragma unroll
    for (int kc = 0; kc < 4; ++kc) {
        h8 bf0 = *(const h8*)&wp[(((w * 2 + 0) * 4 + kc) * 64 + lane) * 8];
        h8 bf1 = *(const h8*)&wp[(((w * 2 + 1) * 4 + kc) * 64 + lane) * 8];
        int co = ((kc * 4 + quad) ^ (cl & 7)) << 3;
        h8 af[4];
#pragma unroll
        for (int rt = 0; rt < 4; ++rt)
            af[rt] = *(const h8*)&X[(rt * 16 + cl) * 128 + co];
#pragma unroll
        for (int rt = 0; rt < 4; ++rt) {
            acc[rt][0] = __builtin_amdgcn_mfma_f32_16x16x32_f16(af[rt], bf0, acc[rt][0], 0, 0, 0);
            acc[rt][1] = __builtin_amdgcn_mfma_f32_16x16x32_f16(af[rt], bf1, acc[rt][1], 0, 0, 0);
        }
    }
}

// ---------------------------------------------------------------------------
// Kernels
// ---------------------------------------------------------------------------

// mlp1 (32-row tiles, blocks 0..127, slot stats) + fused prep (blocks 128..208:
// zero sums2+cvec, pack w2/w4 layer-2 weights to fp16 frag layout).
__global__ __launch_bounds__(256) void k_mlp1p(const float* __restrict__ x,
                                               const float* __restrict__ w1,
                                               const float* __restrict__ b1,
                                               const float* __restrict__ w2,
                                               const float* __restrict__ b2,
                                               float* __restrict__ h1,
                                               float* __restrict__ slots,
                                               float* __restrict__ sums2,
                                               float* __restrict__ cvec,
                                               const float* __restrict__ w2src,
                                               _Float16* __restrict__ w2p,
                                               const float* __restrict__ w4src,
                                               _Float16* __restrict__ w4p) {
    __shared__ float Xs[32 * 44];
    __shared__ float As[32 * 132];
    int tid = threadIdx.x;
    int blk = blockIdx.x;
    if (blk >= 128) {
        if (blk < 193) {  // zeroing
            int i = (blk - 128) * 256 + tid;
            if (i < 16384) sums2[i] = 0.f;
            else if (i < 16512) cvec[i - 16384] = 0.f;
        } else {  // weight packing
            int second = blk >= 201;
            const float* src = second ? w4src : w2src;
            _Float16* wp = second ? w4p : w2p;
            int flat = (blk - (second ? 201 : 193)) * 256 + tid;  // 0..2047
            int g = flat >> 6, L = flat & 63;
            int ct = g >> 2, kc = g & 3;
            int nn = ct * 16 + (L & 15), k0 = kc * 32 + (L >> 4) * 8;
            h8 v;
#pragma unroll
            for (int j = 0; j < 8; ++j) v[j] = (_Float16)src[(k0 + j) * 128 + nn];
            *(h8*)&wp[flat * 8] = v;
        }
        return;
    }
    int tx = tid & 15, ty = tid >> 4;
    int r0 = blk * 32;
    for (int idx = tid; idx < 32 * 40; idx += 256) {
        int r = idx / 40, k = idx - r * 40;
        int rr = r0 + r, b = rr >> 6, n = rr & 63, t = k >> 2, d = k & 3;
        Xs[r * 44 + k] = x[((b * 10 + t) * 64 + n) * 4 + d];
    }
    __syncthreads();
    float acc[2][8] = {};
    gemm32_globalW(Xs, 44, w1, 40, acc, tx, ty);
    float vals[2][8];
    bias_elu32(acc, b1, vals, tx);
    int ca = 4 * tx, cb = 64 + 4 * tx;
#pragma unroll
    for (int j = 0; j < 2; ++j) {
        int r = ty + 16 * j;
#pragma unroll
        for (int u = 0; u < 4; ++u) {
            As[r * 132 + ca + u] = vals[j][u];
            As[r * 132 + cb + u] = vals[j][u + 4];
        }
    }
    __syncthreads();
    float acc2[2][8] = {};
    gemm32_globalW(As, 132, w2, 128, acc2, tx, ty);
    float vals2[2][8];
    bias_elu32(acc2, b2, vals2, tx);
    store_tile32(h1, r0, vals2, tx, ty);
    stats_tail32_store(vals2, As, slots + blk * 256, tid, tx, ty);
}

// P/Q precompute with fused BN-coef derivation from nslots plain-store slots.
// 16-row tiles, grid 512 (2 blocks/CU). Optionally zeroes zero4[0:16384)
// distributed across the 512 blocks (pq4).
__global__ __launch_bounds__(256) void k_pqf(const float* __restrict__ h,
                                             const float* __restrict__ slots,
                                             int nslots,
                                             const float* __restrict__ g,
                                             const float* __restrict__ beta,
                                             const float* __restrict__ w,
                                             float* __restrict__ P, float* __restrict__ Q,
                                             float* __restrict__ zero4) {
    __shared__ float Cf[256];
    __shared__ float As[16 * 132];
    int tid = threadIdx.x, tx = tid & 15, ty = tid >> 4;
    int half = blockIdx.x >> 8;
    int r0 = (blockIdx.x & 255) * 16;
    if (zero4 && tid < 32) zero4[blockIdx.x * 32 + tid] = 0.f;
    if (tid < 128) {
        int c = tid;
        float s = 0.f, q = 0.f;
#pragma unroll 8
        for (int t = 0; t < nslots; ++t) {
            s += slots[t * 256 + c];
            q += slots[t * 256 + 128 + c];
        }
        float mean = s * (1.f / 4096.f);
        float var = q * (1.f / 4096.f) - mean * mean;
        float a = g[c] * rsqrtf(var + BN_EPS);
        Cf[c] = a;
        Cf[128 + c] = beta[c] - mean * a;
    }
    __syncthreads();
    const float* Wg = w + half * 128 * 128;
    float* out = half ? Q : P;
    const float4* h4p = (const float4*)h;
#pragma unroll
    for (int i = 0; i < 2; ++i) {
        int f4 = tid + i * 256;
        int r = f4 >> 5, c4 = f4 & 31;
        float4 hv = h4p[(r0 + r) * 32 + c4];
        int cb = c4 * 4;
        float4 v;
        v.x = Cf[cb] * hv.x + Cf[128 + cb];
        v.y = Cf[cb + 1] * hv.y + Cf[128 + cb + 1];
        v.z = Cf[cb + 2] * hv.z + Cf[128 + cb + 2];
        v.w = Cf[cb + 3] * hv.w + Cf[128 + cb + 3];
        *(float4*)(As + r * 132 + c4 * 4) = v;
    }
    __syncthreads();
    float acc[8] = {};
    gemm16_globalW(As, 132, Wg, 128, acc, tx, ty);
    int r = r0 + ty;
    *(float4*)(out + r * 128 + 4 * tx) = make_float4(acc[0], acc[1], acc[2], acc[3]);
    *(float4*)(out + r * 128 + 64 + 4 * tx) = make_float4(acc[4], acc[5], acc[6], acc[7]);
}

// Recv-major fused mlp2 + edge2node + h2 materialization (round-5 proven:
// coalesced stage into swizzled row-major LDS, gemm1_swz, reordered h2 write).
__global__ __launch_bounds__(256, 6) void k_mlp2agg(const float* __restrict__ P2,
                                                    const float* __restrict__ Q2,
                                                    const float* __restrict__ b1,
                                                    const _Float16* __restrict__ w2p,
                                                    const float* __restrict__ b2,
                                                    float* __restrict__ aggraw,
                                                    _Float16* __restrict__ h2,
                                                    float* __restrict__ st) {
    __shared__ __align__(16) _Float16 Afr[9216];
    int tid = threadIdx.x;
    int lane = tid & 63, w = tid >> 6, cl = lane & 15, quad = lane >> 4;
    int b = blockIdx.x >> 6, n0 = blockIdx.x & 63;
    float* stc = st + n0 * 256;
    // --- coalesced stage into row-major swizzled tile X[64][128] fp16 ---
    {
        int c4 = tid & 31;    // float4 column 0..31
        int rsub = tid >> 5;  // 0..7
        const float4* Qr = (const float4*)(Q2 + (b * 64 + n0) * 128);
        const float4* B1 = (const float4*)b1;
        float4 qv = Qr[c4];
        float4 bv = B1[c4];
        float qbx = qv.x + bv.x, qby = qv.y + bv.y;
        float qbz = qv.z + bv.z, qbw = qv.w + bv.w;
        const float4* P4p = (const float4*)(P2 + (size_t)b * 64 * 128);
#pragma unroll
        for (int it = 0; it < 8; ++it) {
            int r = it * 8 + rsub;
            int s0 = (r < 63) ? (r + (r >= n0 ? 1 : 0)) : n0;  // row 63: dummy
            float4 p = P4p[s0 * 32 + c4];
            h4v v;
            v[0] = (_Float16)elu_f(p.x + qbx);
            v[1] = (_Float16)elu_f(p.y + qby);
            v[2] = (_Float16)elu_f(p.z + qbz);
            v[3] = (_Float16)elu_f(p.w + qbw);
            int off = r * 128 + ((((c4 >> 1) ^ (r & 7)) << 3) | ((c4 & 1) << 2));
            *(h4v*)&Afr[off] = v;
        }
    }
    __syncthreads();
    f4v acc[4][2];
#pragma unroll
    for (int rt = 0; rt < 4; ++rt)
#pragma unroll
        for (int c = 0; c < 2; ++c)
            acc[rt][c] = (f4v){0.f, 0.f, 0.f, 0.f};
    gemm1_swz(Afr, w2p, acc, lane, w, cl, quad);
    float v0[2][4][4];
#pragma unroll
    for (int ctl = 0; ctl < 2; ++ctl) {
        int col = (w * 2 + ctl) * 16 + cl;
        float bias = b2[col];
        float a0 = 0.f, sq = 0.f;
#pragma unroll
        for (int rt = 0; rt < 4; ++rt)
#pragma unroll
            for (int i = 0; i < 4; ++i) {
                int row = rt * 16 + quad * 4 + i;
                float va = elu_f(acc[rt][ctl][i] + bias);
                if (row == 63) va = 0.f;
                v0[ctl][rt][i] = va;
                a0 += va;
                sq += va * va;
            }
        a0 += __shfl_xor(a0, 16);
        sq += __shfl_xor(sq, 16);
        a0 += __shfl_xor(a0, 32);
        sq += __shfl_xor(sq, 32);
        if (quad == 0) {
            aggraw[(b * 64 + n0) * 128 + col] = a0;
            atomicAdd(stc + col, a0);
            atomicAdd(stc + 128 + col, sq);
        }
    }
    __syncthreads();
    unsigned short* T0 = (unsigned short*)Afr;
#pragma unroll
    for (int ctl = 0; ctl < 2; ++ctl) {
        int col = (w * 2 + ctl) * 16 + cl;
#pragma unroll
        for (int rt = 0; rt < 4; ++rt)
#pragma unroll
            for (int i = 0; i < 4; ++i) {
                int row = rt * 16 + quad * 4 + i;
                _Float16 ha = (_Float16)v0[ctl][rt][i];
                T0[row * 144 + col] = *(unsigned short*)&ha;
            }
    }
    __syncthreads();
    {
        int rr = tid >> 2, cq = tid & 3;
        if (rr < 63) {
            int s0 = rr + (rr >= n0 ? 1 : 0);
            int e0 = s0 * 63 + (s0 > n0 ? n0 : n0 - 1);
            unsigned short* d0 = (unsigned short*)h2 + ((size_t)b * 4032 + e0) * 128;
#pragma unroll
            for (int i = 0; i < 4; ++i) {
                int off = i * 32 + cq * 8;  // row's 4 lanes contiguous (64B)
                *(uint4*)(d0 + off) = *(uint4*)&T0[rr * 144 + off];
            }
        }
    }
}

// fused BN2-finalize + wcprep: block k derives coef2[k] pair from the 64-slot
// atomic arena, writes it (for mlp3), then scales W4_1[256+k][:] into wcp and
// accumulates cvec.
__global__ __launch_bounds__(128) void k_wcfin(const float* __restrict__ sums2,
                                               const float* __restrict__ g2,
                                               const float* __restrict__ be2,
                                               const float* __restrict__ w41,
                                               _Float16* __restrict__ wcp,
                                               float* __restrict__ cvec,
                                               float* __restrict__ coef2) {
    __shared__ float red[128];
    __shared__ float pr[2];
    int k = blockIdx.x, c = threadIdx.x;  // 128 threads
    red[c] = (c < 64) ? sums2[c * 256 + k] : sums2[(c - 64) * 256 + 128 + k];
    __syncthreads();
    if (c == 0) {
        float s = 0.f, q = 0.f;
#pragma unroll 8
        for (int t = 0; t < 64; ++t) {
            s += red[t];
            q += red[64 + t];
        }
        float mean = s * (1.f / 258048.f);
        float var = q * (1.f / 258048.f) - mean * mean;
        float a = g2[k] * rsqrtf(var + BN_EPS);
        pr[0] = a;
        pr[1] = be2[k] - mean * a;
        coef2[k] = a;
        coef2[128 + k] = pr[1];
    }
    __syncthreads();
    float a2k = pr[0], sh2k = pr[1];
    float wv = w41[(256 + k) * 128 + c];
    int g = (c >> 4) * 4 + (k >> 5);
    int L = ((k >> 3) & 3) * 16 + (c & 15);
    int j = k & 7;
    wcp[(g * 64 + L) * 8 + j] = (_Float16)(a2k * wv);
    atomicAdd(&cvec[c], sh2k * wv);
}

// mlp3 (round-9 proven): 16-row tiles, 256 blocks, 256 stat slots.
__global__ __launch_bounds__(256) void k_mlp3(const float* __restrict__ raw,
                                              const float* __restrict__ coef2,
                                              const float* __restrict__ w1,
                                              const float* __restrict__ b1,
                                              const float* __restrict__ w2,
                                              const float* __restrict__ b2,
                                              float* __restrict__ h3,
                                              float* __restrict__ slots) {
    __shared__ float As[4224];  // staging/GEMM uses 16*132=2112; stats tail uses 4096
    int tid = threadIdx.x, tx = tid & 15, ty = tid >> 4;
    int r0 = blockIdx.x * 16;
    const float4* in4 = (const float4*)raw;
    const float4* av = (const float4*)coef2;
    const float4* cv = (const float4*)(coef2 + 128);
    const float inv63 = 1.f / 63.f;
#pragma unroll
    for (int i = 0; i < 2; ++i) {
        int f4 = tid + i * 256;
        int r = f4 >> 5, c4 = f4 & 31;
        float4 hv = in4[(r0 + r) * 32 + c4];
        float4 a = av[c4], c = cv[c4];
        float4 v;
        v.x = a.x * hv.x * inv63 + c.x;
        v.y = a.y * hv.y * inv63 + c.y;
        v.z = a.z * hv.z * inv63 + c.z;
        v.w = a.w * hv.w * inv63 + c.w;
        *(float4*)(As + r * 132 + c4 * 4) = v;
    }
    __syncthreads();
    float acc[8] = {};
    gemm16_globalW(As, 132, w1, 128, acc, tx, ty);
    float vals[8];
    bias_elu16(acc, b1, vals, tx);
    __syncthreads();
    int ca = 4 * tx, cb = 64 + 4 * tx;
#pragma unroll
    for (int u = 0; u < 4; ++u) {
        As[ty * 132 + ca + u] = vals[u];
        As[ty * 132 + cb + u] = vals[u + 4];
    }
    __syncthreads();
    float acc2[8] = {};
    gemm16_globalW(As, 132, w2, 128, acc2, tx, ty);
    float vals2[8];
    bias_elu16(acc2, b2, vals2, tx);
    int r = r0 + ty;
    *(float4*)(h3 + r * 128 + 4 * tx) = make_float4(vals2[0], vals2[1], vals2[2], vals2[3]);
    *(float4*)(h3 + r * 128 + 64 + 4 * tx) = make_float4(vals2[4], vals2[5], vals2[6], vals2[7]);
    stats_tail16_store(vals2, As, slots + blockIdx.x * 256, tid, tx, ty);
}

// mlp4 edge kernel — ROUND-9 PROVEN VERSION (48.7 µs, VGPR 40, no spills).
// Gather sits between gemm1 and tile2; do NOT hoist it (r10: spilled, +90 MB
// scratch traffic). Bounds (256,6); do NOT raise (r6: spilled).
__global__ __launch_bounds__(256, 6) void k_mlp4r3(const _Float16* __restrict__ h2,
                                                   const float* __restrict__ P4,
                                                   const float* __restrict__ Q4,
                                                   const _Float16* __restrict__ wcp,
                                                   const float* __restrict__ cvec,
                                                   const float* __restrict__ b1,
                                                   const _Float16* __restrict__ w4p2,
                                                   const float* __restrict__ b2,
                                                   unsigned short* __restrict__ h4,
                                                   float* __restrict__ st) {
    __shared__ __align__(16) _Float16 Afr[8192];
    int tid = threadIdx.x;
    int lane = tid & 63, w = tid >> 6, cl = lane & 15, quad = lane >> 4;
    unsigned t0 = blockIdx.x;
    unsigned b0 = t0 / 63;
    unsigned e00 = (t0 - b0 * 63) * 64;
    float* stc = st + (blockIdx.x & 63) * 256;
    {
        const _Float16* hb = h2 + (size_t)t0 * 8192;
#pragma unroll
        for (int i = 0; i < 4; ++i) {
            int u = tid + i * 256;
            int r = u >> 4, c = u & 15;
            h8 v = *(const h8*)&hb[r * 128 + c * 8];
            *(h8*)&Afr[r * 128 + ((c ^ (r & 7)) << 3)] = v;
        }
    }
    __syncthreads();
    f4v acc[4][2];
#pragma unroll
    for (int rt = 0; rt < 4; ++rt)
#pragma unroll
        for (int c = 0; c < 2; ++c)
            acc[rt][c] = (f4v){0.f, 0.f, 0.f, 0.f};
    gemm1_swz(Afr, wcp, acc, lane, w, cl, quad);
    float v0[4][2][4];
    {
        int col0 = w * 32 + cl, col1 = col0 + 16;
        float base0 = b1[col0] + cvec[col0];
        float base1 = b1[col1] + cvec[col1];
        unsigned sA0 = e00 / 63;
        unsigned baseE0 = sA0 * 63;
        unsigned eB0 = baseE0 + 63;
        unsigned sB0 = sA0 < 63u ? sA0 + 1u : sA0;
        const float* PA0 = P4 + (b0 * 64 + sA0) * 128;
        const float* PB0 = P4 + (b0 * 64 + sB0) * 128;
        float pA0c0 = PA0[col0], pA0c1 = PA0[col1];
        float pB0c0 = PB0[col0], pB0c1 = PB0[col1];
        const float* Qb0 = Q4 + (size_t)b0 * 8192;
#pragma unroll
        for (int rt = 0; rt < 4; ++rt)
#pragma unroll
            for (int i = 0; i < 4; ++i) {
                int rr = rt * 16 + quad * 4 + i;
                unsigned e = e00 + rr;
                bool hi = e >= eB0;
                unsigned s = hi ? sB0 : sA0;
                unsigned jj = e - (hi ? eB0 : baseE0);
                unsigned rv = jj + (jj >= s ? 1u : 0u);
                const float* Qr = Qb0 + rv * 128;
                float p0 = hi ? pB0c0 : pA0c0, p1 = hi ? pB0c1 : pA0c1;
                v0[rt][0][i] = elu_f(acc[rt][0][i] + p0 + Qr[col0] + base0);
                v0[rt][1][i] = elu_f(acc[rt][1][i] + p1 + Qr[col1] + base1);
            }
    }
    __syncthreads();
    // tile2: write intermediate X2[row][col] into the same swizzled layout
    {
        int colb0 = w * 32 + cl, colb1 = colb0 + 16;
        int cc0 = colb0 >> 3, cj0 = colb0 & 7;
        int cc1 = colb1 >> 3, cj1 = colb1 & 7;
#pragma unroll
        for (int rt = 0; rt < 4; ++rt)
#pragma unroll
            for (int i = 0; i < 4; ++i) {
                int row = rt * 16 + quad * 4 + i;
                int rx = row & 7;
                Afr[row * 128 + (((cc0 ^ rx) << 3) | cj0)] = (_Float16)v0[rt][0][i];
                Afr[row * 128 + (((cc1 ^ rx) << 3) | cj1)] = (_Float16)v0[rt][1][i];
            }
    }
    __syncthreads();
#pragma unroll
    for (int rt = 0; rt < 4; ++rt)
#pragma unroll
        for (int c = 0; c < 2; ++c)
            acc[rt][c] = (f4v){0.f, 0.f, 0.f, 0.f};
    gemm1_swz(Afr, w4p2, acc, lane, w, cl, quad);
#pragma unroll
    for (int ctl = 0; ctl < 2; ++ctl) {
        int col = (w * 2 + ctl) * 16 + cl;
        float bias = b2[col];
        float s1 = 0.f, s2 = 0.f;
#pragma unroll
        for (int rt = 0; rt < 4; ++rt)
#pragma unroll
            for (int i = 0; i < 4; ++i) {
                float va = elu_f(acc[rt][ctl][i] + bias);
                v0[rt][ctl][i] = va;
                s1 += va;
                s2 += va * va;
            }
        s1 += __shfl_xor(s1, 16);
        s2 += __shfl_xor(s2, 16);
        s1 += __shfl_xor(s1, 32);
        s2 += __shfl_xor(s2, 32);
        if (quad == 0) {
            atomicAdd(stc + col, s1);
            atomicAdd(stc + 128 + col, s2);
        }
    }
    // direct C-layout store: idx = ((cg*4+rt)*4+quad)*64 + cl*4 + i
    {
        unsigned short* o0 = h4 + (size_t)t0 * 8192;
#pragma unroll
        for (int ctl = 0; ctl < 2; ++ctl) {
            int cg = w * 2 + ctl;
#pragma unroll
            for (int rt = 0; rt < 4; ++rt) {
                int idx = ((cg * 4 + rt) * 4 + quad) * 64 + cl * 4;
                h4v a;
#pragma unroll
                for (int i = 0; i < 4; ++i) a[i] = (_Float16)v0[rt][ctl][i];
                *(h4v*)(o0 + idx) = a;
            }
        }
    }
}

// fused BN4-finalize + fc output, reading h4 in C-layout. BN is folded into
// the fc weights: u_k[c] = a[c]*w[c][k]; out = h.u_k + C_k with
// C_k = sum_c sh[c]*w[c][k] + fcb[k].
__global__ __launch_bounds__(256) void k_outf(const unsigned short* __restrict__ h4,
                                              const float* __restrict__ sums4,
                                              const float* __restrict__ g4,
                                              const float* __restrict__ be4,
                                              const float* __restrict__ fcw,
                                              const float* __restrict__ fcb,
                                              float* __restrict__ out) {
    __shared__ float U0[128];
    __shared__ float U1[128];
    __shared__ float Cp[4];
    int tid = threadIdx.x;
    if (tid < 128) {
        int c = tid;
        float s = 0.f, q = 0.f;
#pragma unroll 8
        for (int t = 0; t < 64; ++t) {
            s += sums4[t * 256 + c];
            q += sums4[t * 256 + 128 + c];
        }
        float mean = s * (1.f / 258048.f);
        float var = q * (1.f / 258048.f) - mean * mean;
        float a = g4[c] * rsqrtf(var + BN_EPS);
        float sh = be4[c] - mean * a;
        float w0 = fcw[2 * c], w1 = fcw[2 * c + 1];
        U0[c] = a * w0;
        U1[c] = a * w1;
        float p0 = sh * w0, p1 = sh * w1;
#pragma unroll
        for (int off = 1; off < 64; off <<= 1) {
            p0 += __shfl_xor(p0, off);
            p1 += __shfl_xor(p1, off);
        }
        if ((tid & 63) == 0) {
            Cp[(tid >> 6) * 2] = p0;
            Cp[(tid >> 6) * 2 + 1] = p1;
        }
    }
    __syncthreads();
    float C0 = Cp[0] + Cp[2] + fcb[0];
    float C1 = Cp[1] + Cp[3] + fcb[1];
    int lane = tid & 63, w = tid >> 6;
    int quad = lane >> 4, cl = lane & 15;
    float u0r[8], u1r[8];
#pragma unroll
    for (int cg = 0; cg < 8; ++cg) {
        u0r[cg] = U0[cg * 16 + cl];
        u1r[cg] = U1[cg * 16 + cl];
    }
    size_t tile = (size_t)blockIdx.x * 4 + w;
    const unsigned short* hb = h4 + tile * 8192;
#pragma unroll
    for (int rt = 0; rt < 4; ++rt) {
        float s00 = 0.f, s01 = 0.f, s02 = 0.f, s03 = 0.f;
        float s10 = 0.f, s11 = 0.f, s12 = 0.f, s13 = 0.f;
#pragma unroll
        for (int cg = 0; cg < 8; ++cg) {
            h4v hv = *(const h4v*)(hb + ((cg * 4 + rt) * 4 + quad) * 64 + cl * 4);
            float u0 = u0r[cg], u1 = u1r[cg];
            float x0 = (float)hv[0], x1 = (float)hv[1];
            float x2 = (float)hv[2], x3 = (float)hv[3];
            s00 = fmaf(x0, u0, s00); s01 = fmaf(x1, u0, s01);
            s02 = fmaf(x2, u0, s02); s03 = fmaf(x3, u0, s03);
            s10 = fmaf(x0, u1, s10); s11 = fmaf(x1, u1, s11);
            s12 = fmaf(x2, u1, s12); s13 = fmaf(x3, u1, s13);
        }
#pragma unroll
        for (int off = 1; off < 16; off <<= 1) {
            s00 += __shfl_xor(s00, off); s01 += __shfl_xor(s01, off);
            s02 += __shfl_xor(s02, off); s03 += __shfl_xor(s03, off);
            s10 += __shfl_xor(s10, off); s11 += __shfl_xor(s11, off);
            s12 += __shfl_xor(s12, off); s13 += __shfl_xor(s13, off);
        }
        if (cl == 0) {
            size_t R = tile * 64 + rt * 16 + quad * 4;
            *(float4*)(out + R * 2) =
                make_float4(s00 + C0, s10 + C1, s01 + C0, s11 + C1);
            *(float4*)(out + R * 2 + 4) =
                make_float4(s02 + C0, s12 + C1, s03 + C0, s13 + C1);
        }
    }
}

// ---------------------------------------------------------------------------

extern "C" void kernel_launch(void* const* d_in, const int* in_sizes, int n_in,
                              void* d_out, int out_size, void* d_ws, size_t ws_size,
                              hipStream_t stream) {
    const float* x = (const float*)d_in[0];
    const float* m1_w1 = (const float*)d_in[1];
    const float* m1_b1 = (const float*)d_in[2];
    const float* m1_w2 = (const float*)d_in[3];
    const float* m1_b2 = (const float*)d_in[4];
    const float* m1_g = (const float*)d_in[5];
    const float* m1_be = (const float*)d_in[6];
    const float* m2_w1 = (const float*)d_in[7];
    const float* m2_b1 = (const float*)d_in[8];
    const float* m2_w2 = (const float*)d_in[9];
    const float* m2_b2 = (const float*)d_in[10];
    const float* m2_g = (const float*)d_in[11];
    const float* m2_be = (const float*)d_in[12];
    const float* m3_w1 = (const float*)d_in[13];
    const float* m3_b1 = (const float*)d_in[14];
    const float* m3_w2 = (const float*)d_in[15];
    const float* m3_b2 = (const float*)d_in[16];
    const float* m3_g = (const float*)d_in[17];
    const float* m3_be = (const float*)d_in[18];
    const float* m4_w1 = (const float*)d_in[19];
    const float* m4_b1 = (const float*)d_in[20];
    const float* m4_w2 = (const float*)d_in[21];
    const float* m4_b2 = (const float*)d_in[22];
    const float* m4_g = (const float*)d_in[23];
    const float* m4_be = (const float*)d_in[24];
    const float* fc_w = (const float*)d_in[25];
    const float* fc_b = (const float*)d_in[26];
    float* out = (float*)d_out;

    float* W = (float*)d_ws;
    float* coef2 = W + OFF_COEF;
    float* cvec = W + OFF_CVEC;
    float* h1 = W + OFF_H1;            // aliased: aggraw; sums4 = h1[0:16384)
    float* aggraw = h1;
    float* sums4 = h1;
    float* P2 = W + OFF_P2;            // sums3 slots = P2[0:65536) (P2 dead then)
    float* sums3 = P2;
    float* Q2 = W + OFF_Q2;
    float* h3 = W + OFF_H3;            // sums1 slots = h3[0:32768) (h3 written later)
    float* sums1 = h3;
    float* P4 = W + OFF_P4;            // sums2 arena = P4[0:16384)
    float* sums2 = P4;
    float* Q4 = W + OFF_Q4;
    _Float16* w2p2 = (_Float16*)(W + OFF_W2P);
    _Float16* w4p2 = (_Float16*)(W + OFF_W4P);
    _Float16* wcp = (_Float16*)(W + OFF_WCP);
    _Float16* h2f = (_Float16*)(W + OFF_H4B);             // h2 (fp16), then
    unsigned short* h4b = (unsigned short*)(W + OFF_H4B); // h4 (fp16, C-layout) in place

    if (ws_size < WS_BYTES) return;  // safe-fail diagnostic (no OOB fault)

    k_mlp1p<<<209, 256, 0, stream>>>(x, m1_w1, m1_b1, m1_w2, m1_b2, h1, sums1,
                                     sums2, cvec, m2_w2, w2p2, m4_w2, w4p2);
    k_pqf<<<512, 256, 0, stream>>>(h1, sums1, 128, m1_g, m1_be, m2_w1, P2, Q2, nullptr);
    k_mlp2agg<<<4096, 256, 0, stream>>>(P2, Q2, m2_b1, w2p2, m2_b2, aggraw, h2f, sums2);
    k_wcfin<<<128, 128, 0, stream>>>(sums2, m2_g, m2_be, m4_w1, wcp, cvec, coef2);
    k_mlp3<<<256, 256, 0, stream>>>(aggraw, coef2, m3_w1, m3_b1, m3_w2, m3_b2, h3, sums3);
    k_pqf<<<512, 256, 0, stream>>>(h3, sums3, 256, m3_g, m3_be, m4_w1, P4, Q4, sums4);
    k_mlp4r3<<<4032, 256, 0, stream>>>(h2f, P4, Q4, wcp, cvec, m4_b1, w4p2, m4_b2,
                                       h4b, sums4);
    k_outf<<<1008, 256, 0, stream>>>(h4b, sums4, m4_g, m4_be, fc_w, fc_b, out);
}